// Round 1
// baseline (475.904 us; speedup 1.0000x reference)
//
#include <hip/hip_runtime.h>
#include <hip/hip_bf16.h>

#define DMODEL 1024
#define NHEADS 16
#define HDIM 64

typedef __bf16 bf16_t;
typedef __bf16 bf16x8 __attribute__((ext_vector_type(8)));
typedef float  f32x4  __attribute__((ext_vector_type(4)));

__device__ __forceinline__ bf16_t f2bf(float f) {
    unsigned int u = __builtin_bit_cast(unsigned int, f);
    u += 0x7FFF + ((u >> 16) & 1);           // RNE
    unsigned short h = (unsigned short)(u >> 16);
    return __builtin_bit_cast(bf16_t, h);
}

__device__ __forceinline__ void gld_lds16(const bf16_t* g, bf16_t* l) {
    __builtin_amdgcn_global_load_lds(
        (const __attribute__((address_space(1))) unsigned int*)g,
        (__attribute__((address_space(3))) unsigned int*)l, 16, 0, 0);
}

// ---------------- fp32 -> bf16 cast (weights) ----------------
__global__ __launch_bounds__(256) void cast_kernel(const float* __restrict__ in,
                                                   bf16_t* __restrict__ out, int n) {
    int i = blockIdx.x * blockDim.x + threadIdx.x;
    int stride = gridDim.x * blockDim.x;
    for (int idx = i * 4; idx < n; idx += stride * 4) {
        float4 v = *reinterpret_cast<const float4*>(in + idx);
        union { bf16_t b[4]; uint2 u; } p;
        p.b[0] = f2bf(v.x); p.b[1] = f2bf(v.y); p.b[2] = f2bf(v.z); p.b[3] = f2bf(v.w);
        *reinterpret_cast<uint2*>(out + idx) = p.u;
    }
}

// ---------------- GEMM: C[m,n] = sum_k A[m,k]*W[n,k] + bias[n] ----------------
// A: [M,K] (fp32 if AF32 else bf16), W: [N,K] bf16, bias fp32 [N]
// 128x128 tile, BK=32, 256 threads (4 waves, each 64x64 out).
template <int AF32, int OF32>
__global__ __launch_bounds__(256) void gemm_bt(const void* __restrict__ Ain,
                                               const bf16_t* __restrict__ W,
                                               const float* __restrict__ bias,
                                               void* __restrict__ Cout,
                                               int M, int N, int K) {
    __shared__ bf16_t Asmem[128 * 32];
    __shared__ bf16_t Bsmem[128 * 32];
    const int m0 = blockIdx.x * 128;
    const int n0 = blockIdx.y * 128;
    const int tid = threadIdx.x;
    const int wave = tid >> 6, lane = tid & 63;
    const int wm = wave >> 1, wn = wave & 1;
    const int lr = lane & 15, lg = lane >> 4;

    f32x4 acc[4][4];
#pragma unroll
    for (int mi = 0; mi < 4; ++mi)
#pragma unroll
        for (int ni = 0; ni < 4; ++ni) acc[mi][ni] = (f32x4){0.f, 0.f, 0.f, 0.f};

    for (int kt = 0; kt < K; kt += 32) {
        // ---- stage A tile [128][32] ----
        if (AF32) {
            const float* Af = (const float*)Ain;
            const int row = tid >> 1;
            const int colb = (tid & 1) * 16;
#pragma unroll
            for (int j = 0; j < 4; ++j) {
                int col = colb + j * 4;
                float4 v = *reinterpret_cast<const float4*>(Af + (size_t)(m0 + row) * K + kt + col);
                union { bf16_t b[4]; uint2 u; } p;
                p.b[0] = f2bf(v.x); p.b[1] = f2bf(v.y); p.b[2] = f2bf(v.z); p.b[3] = f2bf(v.w);
                *reinterpret_cast<uint2*>(&Asmem[row * 32 + col]) = p.u;
            }
        } else {
            const bf16_t* Ab = (const bf16_t*)Ain;
#pragma unroll
            for (int i = 0; i < 2; ++i) {
                int c = wave * 2 + i;
                int row = c * 16 + (lane >> 2);
                int col = (lane & 3) * 8;
                gld_lds16(Ab + (size_t)(m0 + row) * K + kt + col, &Asmem[c * 512]);
            }
        }
        // ---- stage B tile [128][32] (bf16 weights, async direct-to-LDS) ----
#pragma unroll
        for (int i = 0; i < 2; ++i) {
            int c = wave * 2 + i;
            int row = c * 16 + (lane >> 2);
            int col = (lane & 3) * 8;
            gld_lds16(W + (size_t)(n0 + row) * K + kt + col, &Bsmem[c * 512]);
        }
        __syncthreads();

        bf16x8 af[4], bfr[4];
#pragma unroll
        for (int mi = 0; mi < 4; ++mi)
            af[mi] = *reinterpret_cast<const bf16x8*>(&Asmem[(wm * 64 + mi * 16 + lr) * 32 + lg * 8]);
#pragma unroll
        for (int ni = 0; ni < 4; ++ni)
            bfr[ni] = *reinterpret_cast<const bf16x8*>(&Bsmem[(wn * 64 + ni * 16 + lr) * 32 + lg * 8]);
#pragma unroll
        for (int mi = 0; mi < 4; ++mi)
#pragma unroll
            for (int ni = 0; ni < 4; ++ni)
                acc[mi][ni] = __builtin_amdgcn_mfma_f32_16x16x32_bf16(af[mi], bfr[ni], acc[mi][ni], 0, 0, 0);
        __syncthreads();
    }

    // ---- epilogue: D layout row=(lane>>4)*4+r, col=lane&15 (m89-verified) ----
#pragma unroll
    for (int mi = 0; mi < 4; ++mi) {
        int row = m0 + wm * 64 + mi * 16 + lg * 4;
#pragma unroll
        for (int ni = 0; ni < 4; ++ni) {
            int col = n0 + wn * 64 + ni * 16 + lr;
            float bv = bias[col];
#pragma unroll
            for (int r = 0; r < 4; ++r) {
                float v = acc[mi][ni][r] + bv;
                if (OF32)
                    ((float*)Cout)[(size_t)(row + r) * N + col] = v;
                else
                    ((bf16_t*)Cout)[(size_t)(row + r) * N + col] = f2bf(v);
            }
        }
    }
}

// ---------------- flash attention ----------------
// grid: x = S/64 (q tiles), y = B*NHEADS. 256 threads = 4 waves, each 16 q rows.
// Q/K/V in [B*S, DMODEL] layout, head h occupies cols h*64..h*64+63.
__global__ __launch_bounds__(256) void attn_kernel(const bf16_t* __restrict__ Qp,
                                                   const bf16_t* __restrict__ Kp,
                                                   const bf16_t* __restrict__ Vp,
                                                   bf16_t* __restrict__ AO, int S) {
    __shared__ bf16_t Ks[64 * 72];       // [key][dim], row pad 72 (conflict-free)
    __shared__ bf16_t Vt[64 * 72];       // [dim][key] transposed
    __shared__ bf16_t Ps[4][16 * 72];    // per-wave P round-trip buffer
    const int tid = threadIdx.x;
    const int wave = tid >> 6, lane = tid & 63;
    const int lr = lane & 15, lg = lane >> 4;
    const int bh = blockIdx.y;
    const int b = bh >> 4, h = bh & 15;
    const int qt = blockIdx.x;
    const size_t base = ((size_t)b * S) * DMODEL + (size_t)h * HDIM;

    const int qrow = qt * 64 + wave * 16 + lr;
    bf16x8 qf[2];
    qf[0] = *reinterpret_cast<const bf16x8*>(Qp + base + (size_t)qrow * DMODEL + lg * 8);
    qf[1] = *reinterpret_cast<const bf16x8*>(Qp + base + (size_t)qrow * DMODEL + 32 + lg * 8);

    f32x4 Oacc[4];
#pragma unroll
    for (int i = 0; i < 4; ++i) Oacc[i] = (f32x4){0.f, 0.f, 0.f, 0.f};
    float m_r[4] = {-1e30f, -1e30f, -1e30f, -1e30f};
    float l_r[4] = {0.f, 0.f, 0.f, 0.f};

    for (int kv = 0; kv < S; kv += 64) {
        __syncthreads();  // protect LDS from overwrite while prev iter still reading
#pragma unroll
        for (int i = 0; i < 2; ++i) {
            int idx = tid + i * 256;       // 512 chunks of 8 bf16
            int key = idx >> 3;
            int dim = (idx & 7) * 8;
            const size_t g = base + (size_t)(kv + key) * DMODEL + dim;
            bf16x8 kvv = *reinterpret_cast<const bf16x8*>(Kp + g);
            *reinterpret_cast<bf16x8*>(&Ks[key * 72 + dim]) = kvv;
            bf16x8 vv = *reinterpret_cast<const bf16x8*>(Vp + g);
#pragma unroll
            for (int j = 0; j < 8; ++j) Vt[(dim + j) * 72 + key] = vv[j];
        }
        __syncthreads();

        // scores: Q(16x64) @ K^T -> 16x64, 4 key groups
        f32x4 sc[4];
#pragma unroll
        for (int nt = 0; nt < 4; ++nt) {
            f32x4 a = (f32x4){0.f, 0.f, 0.f, 0.f};
#pragma unroll
            for (int kk = 0; kk < 2; ++kk) {
                bf16x8 kf = *reinterpret_cast<const bf16x8*>(&Ks[(nt * 16 + lr) * 72 + kk * 32 + lg * 8]);
                a = __builtin_amdgcn_mfma_f32_16x16x32_bf16(qf[kk], kf, a, 0, 0, 0);
            }
            sc[nt] = a * 0.125f;   // 1/sqrt(64)
        }

        // online softmax per row (rows = lg*4 + r; 16 key-lanes share a row)
#pragma unroll
        for (int r = 0; r < 4; ++r) {
            float mx = fmaxf(fmaxf(sc[0][r], sc[1][r]), fmaxf(sc[2][r], sc[3][r]));
#pragma unroll
            for (int d = 1; d < 16; d <<= 1) mx = fmaxf(mx, __shfl_xor(mx, d, 64));
            float mnew = fmaxf(m_r[r], mx);
            float fsc = __expf(m_r[r] - mnew);
            float p0 = __expf(sc[0][r] - mnew);
            float p1 = __expf(sc[1][r] - mnew);
            float p2 = __expf(sc[2][r] - mnew);
            float p3 = __expf(sc[3][r] - mnew);
            float s = p0 + p1 + p2 + p3;
#pragma unroll
            for (int d = 1; d < 16; d <<= 1) s += __shfl_xor(s, d, 64);
            l_r[r] = l_r[r] * fsc + s;
            m_r[r] = mnew;
#pragma unroll
            for (int nt2 = 0; nt2 < 4; ++nt2) Oacc[nt2][r] *= fsc;
            int prow = lg * 4 + r;
            Ps[wave][prow * 72 +  0 + lr] = f2bf(p0);
            Ps[wave][prow * 72 + 16 + lr] = f2bf(p1);
            Ps[wave][prow * 72 + 32 + lr] = f2bf(p2);
            Ps[wave][prow * 72 + 48 + lr] = f2bf(p3);
        }

        // PV: P(16x64) @ V(64x64) -> accumulate O(16x64)
        bf16x8 pa[2];
#pragma unroll
        for (int kk = 0; kk < 2; ++kk)
            pa[kk] = *reinterpret_cast<const bf16x8*>(&Ps[wave][lr * 72 + kk * 32 + lg * 8]);
#pragma unroll
        for (int nt2 = 0; nt2 < 4; ++nt2) {
#pragma unroll
            for (int kk = 0; kk < 2; ++kk) {
                bf16x8 vf = *reinterpret_cast<const bf16x8*>(&Vt[(nt2 * 16 + lr) * 72 + kk * 32 + lg * 8]);
                Oacc[nt2] = __builtin_amdgcn_mfma_f32_16x16x32_bf16(pa[kk], vf, Oacc[nt2], 0, 0, 0);
            }
        }
    }

    // epilogue: normalize and store bf16
#pragma unroll
    for (int nt2 = 0; nt2 < 4; ++nt2) {
        int col = nt2 * 16 + lr;
#pragma unroll
        for (int r = 0; r < 4; ++r) {
            int row = qt * 64 + wave * 16 + lg * 4 + r;
            float v = Oacc[nt2][r] / l_r[r];
            AO[base + (size_t)row * DMODEL + col] = f2bf(v);
        }
    }
}

extern "C" void kernel_launch(void* const* d_in, const int* in_sizes, int n_in,
                              void* d_out, int out_size, void* d_ws, size_t ws_size,
                              hipStream_t stream) {
    const float* q  = (const float*)d_in[0];
    const float* k  = (const float*)d_in[1];
    const float* v  = (const float*)d_in[2];
    const float* Wq = (const float*)d_in[3];
    const float* bq = (const float*)d_in[4];
    const float* Wk = (const float*)d_in[5];
    const float* bk = (const float*)d_in[6];
    const float* Wv = (const float*)d_in[7];
    const float* bv = (const float*)d_in[8];
    const float* Wo = (const float*)d_in[9];
    const float* bo = (const float*)d_in[10];

    const int M = in_sizes[0] / DMODEL;   // B*S
    const int S = 2048;
    const int B = M / S;

    bf16_t* ws  = (bf16_t*)d_ws;
    const size_t WSZ = (size_t)DMODEL * DMODEL;
    const size_t MSZ = (size_t)M * DMODEL;
    bf16_t* Wqb = ws;
    bf16_t* Wkb = Wqb + WSZ;
    bf16_t* Wvb = Wkb + WSZ;
    bf16_t* Wob = Wvb + WSZ;
    bf16_t* Qp  = Wob + WSZ;
    bf16_t* Kp  = Qp + MSZ;
    bf16_t* Vp  = Kp + MSZ;
    bf16_t* AO  = Vp + MSZ;

    cast_kernel<<<1024, 256, 0, stream>>>(Wq, Wqb, DMODEL * DMODEL);
    cast_kernel<<<1024, 256, 0, stream>>>(Wk, Wkb, DMODEL * DMODEL);
    cast_kernel<<<1024, 256, 0, stream>>>(Wv, Wvb, DMODEL * DMODEL);
    cast_kernel<<<1024, 256, 0, stream>>>(Wo, Wob, DMODEL * DMODEL);

    dim3 gg(M / 128, DMODEL / 128);
    gemm_bt<1, 0><<<gg, 256, 0, stream>>>(q, Wqb, bq, Qp, M, DMODEL, DMODEL);
    gemm_bt<1, 0><<<gg, 256, 0, stream>>>(k, Wkb, bk, Kp, M, DMODEL, DMODEL);
    gemm_bt<1, 0><<<gg, 256, 0, stream>>>(v, Wvb, bv, Vp, M, DMODEL, DMODEL);

    attn_kernel<<<dim3(S / 64, B * NHEADS), 256, 0, stream>>>(Qp, Kp, Vp, AO, S);

    gemm_bt<0, 1><<<gg, 256, 0, stream>>>(AO, Wob, bo, d_out, M, DMODEL, DMODEL);
}

// Round 2
// 323.898 us; speedup vs baseline: 1.4693x; 1.4693x over previous
//
#include <hip/hip_runtime.h>
#include <hip/hip_bf16.h>

#define DMODEL 1024
#define NHEADS 16
#define HDIM 64

typedef __bf16 bf16_t;
typedef __bf16 bf16x8 __attribute__((ext_vector_type(8)));
typedef float  f32x4  __attribute__((ext_vector_type(4)));

__device__ __forceinline__ bf16_t f2bf(float f) {
    unsigned int u = __builtin_bit_cast(unsigned int, f);
    u += 0x7FFF + ((u >> 16) & 1);           // RNE
    unsigned short h = (unsigned short)(u >> 16);
    return __builtin_bit_cast(bf16_t, h);
}

__device__ __forceinline__ unsigned pk2(float lo, float hi) {
    unsigned a = (unsigned)__builtin_bit_cast(unsigned short, f2bf(lo));
    unsigned b = (unsigned)__builtin_bit_cast(unsigned short, f2bf(hi));
    return a | (b << 16);
}

__device__ __forceinline__ void gld_lds16(const bf16_t* g, bf16_t* l) {
    __builtin_amdgcn_global_load_lds(
        (const __attribute__((address_space(1))) unsigned int*)g,
        (__attribute__((address_space(3))) unsigned int*)l, 16, 0, 0);
}

// ---------------- fp32 -> bf16 cast (weights) ----------------
__global__ __launch_bounds__(256) void cast_kernel(const float* __restrict__ in,
                                                   bf16_t* __restrict__ out, int n) {
    int i = blockIdx.x * blockDim.x + threadIdx.x;
    int stride = gridDim.x * blockDim.x;
    for (int idx = i * 4; idx < n; idx += stride * 4) {
        float4 v = *reinterpret_cast<const float4*>(in + idx);
        union { bf16_t b[4]; uint2 u; } p;
        p.b[0] = f2bf(v.x); p.b[1] = f2bf(v.y); p.b[2] = f2bf(v.z); p.b[3] = f2bf(v.w);
        *reinterpret_cast<uint2*>(out + idx) = p.u;
    }
}

// ---------------- GEMM: C[m,n] = (sum_k A[m,k]*W[n,k] + bias[n]) * scale ----------------
// OMODE 0: bf16 row-major [M,N]; 1: f32 row-major; 2: bf16 transposed [B,H,D,S] (for V)
template <int AF32, int OMODE>
__global__ __launch_bounds__(256) void gemm_bt(const void* __restrict__ Ain,
                                               const bf16_t* __restrict__ W,
                                               const float* __restrict__ bias,
                                               void* __restrict__ Cout,
                                               int M, int N, int K, float scale, int S) {
    __shared__ bf16_t Asmem[128 * 32];
    __shared__ bf16_t Bsmem[128 * 32];
    const int m0 = blockIdx.x * 128;
    const int n0 = blockIdx.y * 128;
    const int tid = threadIdx.x;
    const int wave = tid >> 6, lane = tid & 63;
    const int wm = wave >> 1, wn = wave & 1;
    const int lr = lane & 15, lg = lane >> 4;

    f32x4 acc[4][4];
#pragma unroll
    for (int mi = 0; mi < 4; ++mi)
#pragma unroll
        for (int ni = 0; ni < 4; ++ni) acc[mi][ni] = (f32x4){0.f, 0.f, 0.f, 0.f};

    for (int kt = 0; kt < K; kt += 32) {
        if (AF32) {
            const float* Af = (const float*)Ain;
            const int row = tid >> 1;
            const int colb = (tid & 1) * 16;
#pragma unroll
            for (int j = 0; j < 4; ++j) {
                int col = colb + j * 4;
                float4 v = *reinterpret_cast<const float4*>(Af + (size_t)(m0 + row) * K + kt + col);
                union { bf16_t b[4]; uint2 u; } p;
                p.b[0] = f2bf(v.x); p.b[1] = f2bf(v.y); p.b[2] = f2bf(v.z); p.b[3] = f2bf(v.w);
                *reinterpret_cast<uint2*>(&Asmem[row * 32 + col]) = p.u;
            }
        } else {
            const bf16_t* Ab = (const bf16_t*)Ain;
#pragma unroll
            for (int i = 0; i < 2; ++i) {
                int c = wave * 2 + i;
                int row = c * 16 + (lane >> 2);
                int col = (lane & 3) * 8;
                gld_lds16(Ab + (size_t)(m0 + row) * K + kt + col, &Asmem[c * 512]);
            }
        }
#pragma unroll
        for (int i = 0; i < 2; ++i) {
            int c = wave * 2 + i;
            int row = c * 16 + (lane >> 2);
            int col = (lane & 3) * 8;
            gld_lds16(W + (size_t)(n0 + row) * K + kt + col, &Bsmem[c * 512]);
        }
        __syncthreads();

        bf16x8 af[4], bfr[4];
#pragma unroll
        for (int mi = 0; mi < 4; ++mi)
            af[mi] = *reinterpret_cast<const bf16x8*>(&Asmem[(wm * 64 + mi * 16 + lr) * 32 + lg * 8]);
#pragma unroll
        for (int ni = 0; ni < 4; ++ni)
            bfr[ni] = *reinterpret_cast<const bf16x8*>(&Bsmem[(wn * 64 + ni * 16 + lr) * 32 + lg * 8]);
#pragma unroll
        for (int mi = 0; mi < 4; ++mi)
#pragma unroll
            for (int ni = 0; ni < 4; ++ni)
                acc[mi][ni] = __builtin_amdgcn_mfma_f32_16x16x32_bf16(af[mi], bfr[ni], acc[mi][ni], 0, 0, 0);
        __syncthreads();
    }

#pragma unroll
    for (int mi = 0; mi < 4; ++mi) {
        int row = m0 + wm * 64 + mi * 16 + lg * 4;
#pragma unroll
        for (int ni = 0; ni < 4; ++ni) {
            int col = n0 + wn * 64 + ni * 16 + lr;
            float bv = bias[col];
            if (OMODE == 2) {
                union { bf16_t b[4]; uint2 u; } pq;
#pragma unroll
                for (int r = 0; r < 4; ++r) pq.b[r] = f2bf((acc[mi][ni][r] + bv) * scale);
                int b_ = row / S, s_ = row % S;
                size_t addr = (((size_t)b_ * NHEADS + (col >> 6)) * HDIM + (col & 63)) * (size_t)S + s_;
                *reinterpret_cast<uint2*>((bf16_t*)Cout + addr) = pq.u;
            } else {
#pragma unroll
                for (int r = 0; r < 4; ++r) {
                    float v = (acc[mi][ni][r] + bv) * scale;
                    if (OMODE == 1)
                        ((float*)Cout)[(size_t)(row + r) * N + col] = v;
                    else
                        ((bf16_t*)Cout)[(size_t)(row + r) * N + col] = f2bf(v);
                }
            }
        }
    }
}

// ---------------- flash attention (swapped-operand, in-register softmax) ----------------
// grid: x = S/64 (q tiles), y = B*NHEADS. 256 threads = 4 waves, each 16 q rows.
// Qp/Kp: [B*S, DMODEL] bf16 (Q pre-scaled by 0.125*log2e). VtG: [B,H,D,S] bf16.
__global__ __launch_bounds__(256) void attn_kernel(const bf16_t* __restrict__ Qp,
                                                   const bf16_t* __restrict__ Kp,
                                                   const bf16_t* __restrict__ VtG,
                                                   bf16_t* __restrict__ AO, int S) {
    __shared__ bf16_t Ks[64 * 64];    // [key][dim], 16B blocks XOR-swizzled by (key&7)
    __shared__ bf16_t Vts[64 * 64];   // [dim][key], 16B blocks XOR-swizzled by (dim&7)
    const int tid = threadIdx.x;
    const int wave = tid >> 6, lane = tid & 63;
    const int lr = lane & 15, lg = lane >> 4;
    const int bh = blockIdx.y;
    const int b = bh >> 4, h = bh & 15;
    const int qt = blockIdx.x;
    const size_t base = ((size_t)b * S) * DMODEL + (size_t)h * HDIM;
    const size_t vbase = (size_t)bh * HDIM * (size_t)S;

    // Q fragment (B-operand): col=q=lr, k = lg*8+e (+32 for qf[1])
    const int qrow = qt * 64 + wave * 16 + lr;
    bf16x8 qf[2];
    qf[0] = *reinterpret_cast<const bf16x8*>(Qp + base + (size_t)qrow * DMODEL + lg * 8);
    qf[1] = *reinterpret_cast<const bf16x8*>(Qp + base + (size_t)qrow * DMODEL + 32 + lg * 8);

    f32x4 Oacc[4];
#pragma unroll
    for (int i = 0; i < 4; ++i) Oacc[i] = (f32x4){0.f, 0.f, 0.f, 0.f};
    float m_r = -1e30f, l_r = 0.f;   // log2-domain max, linear sum (per q-row lr)

    // staging geometry: row r0 = tid>>3 (0..31; +32 second issue), 16B block cb = tid&7
    const int r0 = tid >> 3;
    const int swz = ((tid & 7) ^ (r0 & 7)) * 8;   // (r0+32)&7 == r0&7

    for (int kv = 0; kv < S; kv += 64) {
        __syncthreads();
        gld_lds16(Kp + base + (size_t)(kv + r0) * DMODEL + swz, &Ks[wave * 512]);
        gld_lds16(Kp + base + (size_t)(kv + r0 + 32) * DMODEL + swz, &Ks[2048 + wave * 512]);
        gld_lds16(VtG + vbase + (size_t)r0 * S + kv + swz, &Vts[wave * 512]);
        gld_lds16(VtG + vbase + (size_t)(r0 + 32) * S + kv + swz, &Vts[2048 + wave * 512]);
        __syncthreads();

        // S^T = mfma(A=K rows, B=Q): lane holds S[q=lr][key = nt*16 + lg*4 + r]
        f32x4 sc[4];
#pragma unroll
        for (int nt = 0; nt < 4; ++nt) {
            f32x4 a = (f32x4){0.f, 0.f, 0.f, 0.f};
#pragma unroll
            for (int kk = 0; kk < 2; ++kk) {
                bf16x8 kf = *reinterpret_cast<const bf16x8*>(
                    &Ks[(nt * 16 + lr) * 64 + (((kk * 4 + lg) ^ (lr & 7)) * 8)]);
                a = __builtin_amdgcn_mfma_f32_16x16x32_bf16(kf, qf[kk], a, 0, 0, 0);
            }
            sc[nt] = a;
        }

        // in-register online softmax (log2 domain; scale already folded into Q)
        float mx = sc[0][0];
#pragma unroll
        for (int nt = 0; nt < 4; ++nt)
#pragma unroll
            for (int r = 0; r < 4; ++r) mx = fmaxf(mx, sc[nt][r]);
        mx = fmaxf(mx, __shfl_xor(mx, 16, 64));
        mx = fmaxf(mx, __shfl_xor(mx, 32, 64));
        float mnew = fmaxf(m_r, mx);
        float fsc = __builtin_amdgcn_exp2f(m_r - mnew);
        float p[4][4];
        float ssum = 0.f;
#pragma unroll
        for (int nt = 0; nt < 4; ++nt)
#pragma unroll
            for (int r = 0; r < 4; ++r) {
                p[nt][r] = __builtin_amdgcn_exp2f(sc[nt][r] - mnew);
                ssum += p[nt][r];
            }
        ssum += __shfl_xor(ssum, 16, 64);
        ssum += __shfl_xor(ssum, 32, 64);
        l_r = l_r * fsc + ssum;
        m_r = mnew;

        // rescale O (rows are q = lg*4+r; fsc lives at lane lr=q, lg=0)
#pragma unroll
        for (int r = 0; r < 4; ++r) {
            float fr = __shfl(fsc, lg * 4 + r, 64);
#pragma unroll
            for (int nt2 = 0; nt2 < 4; ++nt2) Oacc[nt2][r] *= fr;
        }

        // pack P to bf16 pairs: w0[nt]=keys{16nt+4lg,+1}, w1[nt]={+2,+3}
        unsigned w0[4], w1[4];
#pragma unroll
        for (int nt = 0; nt < 4; ++nt) {
            w0[nt] = pk2(p[nt][0], p[nt][1]);
            w1[nt] = pk2(p[nt][2], p[nt][3]);
        }
        // redistribute to A-fragment: lane needs keys 32kk+8lg+{0..7}
        const int s0 = lr + ((lg & 1) << 5);
        const int s1 = s0 + 16;
        const int hi = lg >> 1;
        bf16x8 pa[2];
#pragma unroll
        for (int kk = 0; kk < 2; ++kk) {
            unsigned a0 = (unsigned)__shfl((int)w0[2 * kk], s0, 64);
            unsigned b0 = (unsigned)__shfl((int)w0[2 * kk + 1], s0, 64);
            unsigned a1 = (unsigned)__shfl((int)w1[2 * kk], s0, 64);
            unsigned b1 = (unsigned)__shfl((int)w1[2 * kk + 1], s0, 64);
            unsigned a2 = (unsigned)__shfl((int)w0[2 * kk], s1, 64);
            unsigned b2 = (unsigned)__shfl((int)w0[2 * kk + 1], s1, 64);
            unsigned a3 = (unsigned)__shfl((int)w1[2 * kk], s1, 64);
            unsigned b3 = (unsigned)__shfl((int)w1[2 * kk + 1], s1, 64);
            union { unsigned u[4]; bf16x8 v; } pu;
            pu.u[0] = hi ? b0 : a0;
            pu.u[1] = hi ? b1 : a1;
            pu.u[2] = hi ? b2 : a2;
            pu.u[3] = hi ? b3 : a3;
            pa[kk] = pu.v;
        }

        // PV: O[q][d] += P V ; A=pa (rows q), B=V^T rows d from Vts
#pragma unroll
        for (int nt2 = 0; nt2 < 4; ++nt2) {
#pragma unroll
            for (int kk = 0; kk < 2; ++kk) {
                bf16x8 vf = *reinterpret_cast<const bf16x8*>(
                    &Vts[(nt2 * 16 + lr) * 64 + (((kk * 4 + lg) ^ (lr & 7)) * 8)]);
                Oacc[nt2] = __builtin_amdgcn_mfma_f32_16x16x32_bf16(pa[kk], vf, Oacc[nt2], 0, 0, 0);
            }
        }
    }

    // epilogue: rows q = lg*4+r, cols d = nt2*16+lr
#pragma unroll
    for (int r = 0; r < 4; ++r) {
        float lsum = __shfl(l_r, lg * 4 + r, 64);
        float inv = 1.f / lsum;
        int row = qt * 64 + wave * 16 + lg * 4 + r;
#pragma unroll
        for (int nt2 = 0; nt2 < 4; ++nt2)
            AO[base + (size_t)row * DMODEL + nt2 * 16 + lr] = f2bf(Oacc[nt2][r] * inv);
    }
}

extern "C" void kernel_launch(void* const* d_in, const int* in_sizes, int n_in,
                              void* d_out, int out_size, void* d_ws, size_t ws_size,
                              hipStream_t stream) {
    const float* q  = (const float*)d_in[0];
    const float* k  = (const float*)d_in[1];
    const float* v  = (const float*)d_in[2];
    const float* Wq = (const float*)d_in[3];
    const float* bq = (const float*)d_in[4];
    const float* Wk = (const float*)d_in[5];
    const float* bk = (const float*)d_in[6];
    const float* Wv = (const float*)d_in[7];
    const float* bv = (const float*)d_in[8];
    const float* Wo = (const float*)d_in[9];
    const float* bo = (const float*)d_in[10];

    const int M = in_sizes[0] / DMODEL;   // B*S
    const int S = 2048;
    const int B = M / S;

    bf16_t* ws  = (bf16_t*)d_ws;
    const size_t WSZ = (size_t)DMODEL * DMODEL;
    const size_t MSZ = (size_t)M * DMODEL;
    bf16_t* Wqb = ws;
    bf16_t* Wkb = Wqb + WSZ;
    bf16_t* Wvb = Wkb + WSZ;
    bf16_t* Wob = Wvb + WSZ;
    bf16_t* Qp  = Wob + WSZ;
    bf16_t* Kp  = Qp + MSZ;
    bf16_t* VtG = Kp + MSZ;
    bf16_t* AO  = VtG + MSZ;

    cast_kernel<<<1024, 256, 0, stream>>>(Wq, Wqb, DMODEL * DMODEL);
    cast_kernel<<<1024, 256, 0, stream>>>(Wk, Wkb, DMODEL * DMODEL);
    cast_kernel<<<1024, 256, 0, stream>>>(Wv, Wvb, DMODEL * DMODEL);
    cast_kernel<<<1024, 256, 0, stream>>>(Wo, Wob, DMODEL * DMODEL);

    const float qscale = 0.125f * 1.44269504088896f;   // 1/sqrt(64) * log2(e)
    dim3 gg(M / 128, DMODEL / 128);
    gemm_bt<1, 0><<<gg, 256, 0, stream>>>(q, Wqb, bq, Qp, M, DMODEL, DMODEL, qscale, S);
    gemm_bt<1, 0><<<gg, 256, 0, stream>>>(k, Wkb, bk, Kp, M, DMODEL, DMODEL, 1.0f, S);
    gemm_bt<1, 2><<<gg, 256, 0, stream>>>(v, Wvb, bv, VtG, M, DMODEL, DMODEL, 1.0f, S);

    attn_kernel<<<dim3(S / 64, B * NHEADS), 256, 0, stream>>>(Qp, Kp, VtG, AO, S);

    gemm_bt<0, 1><<<gg, 256, 0, stream>>>(AO, Wob, bo, d_out, M, DMODEL, DMODEL, 1.0f, S);
}

// Round 4
// 294.149 us; speedup vs baseline: 1.6179x; 1.1011x over previous
//
#include <hip/hip_runtime.h>
#include <hip/hip_bf16.h>

#define DMODEL 1024
#define NHEADS 16
#define HDIM 64

typedef __bf16 bf16_t;
typedef __bf16 bf16x8 __attribute__((ext_vector_type(8)));
typedef float  f32x4  __attribute__((ext_vector_type(4)));

__device__ __forceinline__ bf16_t f2bf(float f) {
    unsigned int u = __builtin_bit_cast(unsigned int, f);
    u += 0x7FFF + ((u >> 16) & 1);           // RNE
    unsigned short h = (unsigned short)(u >> 16);
    return __builtin_bit_cast(bf16_t, h);
}

__device__ __forceinline__ unsigned cvt_pk_bf16(float lo, float hi) {
    unsigned r;
    asm("v_cvt_pk_bf16_f32 %0, %1, %2" : "=v"(r) : "v"(lo), "v"(hi));
    return r;
}

__device__ __forceinline__ void gld_lds16(const bf16_t* g, bf16_t* l) {
    __builtin_amdgcn_global_load_lds(
        (const __attribute__((address_space(1))) unsigned int*)g,
        (__attribute__((address_space(3))) unsigned int*)l, 16, 0, 0);
}

// ---------------- fp32 -> bf16 cast: 4 weight matrices, one launch ----------------
__global__ __launch_bounds__(256) void cast4(const float* __restrict__ s0,
                                             const float* __restrict__ s1,
                                             const float* __restrict__ s2,
                                             const float* __restrict__ s3,
                                             bf16_t* __restrict__ d, int n) {
    int y = blockIdx.y;
    const float* s = (y == 0) ? s0 : (y == 1) ? s1 : (y == 2) ? s2 : s3;
    bf16_t* dst = d + (size_t)y * n;
    int i = blockIdx.x * blockDim.x + threadIdx.x;
    int stride = gridDim.x * blockDim.x;
    for (int idx = i * 4; idx < n; idx += stride * 4) {
        float4 v = *reinterpret_cast<const float4*>(s + idx);
        uint2 u;
        u.x = cvt_pk_bf16(v.x, v.y);
        u.y = cvt_pk_bf16(v.z, v.w);
        *reinterpret_cast<uint2*>(dst + idx) = u;
    }
}

// ---------------- GEMM: C[m,n] = (sum_k A[m,k]*W[n,k] + bias[n]) * scale ----------------
// AF32: A fp32 (reg-staged, T14 issue-early/write-late) else bf16 (global_load_lds).
// OMODE 0: bf16 row-major; 1: f32 row-major; 2: bf16 transposed [B,H,D,S] (for V)
// Double-buffered LDS (T3-minimal 2-phase).
template <int AF32, int OMODE>
__global__ __launch_bounds__(256) void gemm_bt(const void* __restrict__ Ain,
                                               const bf16_t* __restrict__ W,
                                               const float* __restrict__ bias,
                                               void* __restrict__ Cout,
                                               int M, int N, int K, float scale, int S) {
    __shared__ bf16_t Asmem[2][128 * 32];
    __shared__ bf16_t Bsmem[2][128 * 32];
    const int m0 = blockIdx.x * 128;
    const int n0 = blockIdx.y * 128;
    const int tid = threadIdx.x;
    const int wave = tid >> 6, lane = tid & 63;
    const int wm = wave >> 1, wn = wave & 1;
    const int lr = lane & 15, lg = lane >> 4;
    const int srow = lane >> 2, scol = (lane & 3) * 8;   // gld_lds geometry
    const int a_r = tid >> 1, a_c = (tid & 1) * 16;      // fp32-A geometry

    const float* Af = (const float*)Ain;
    const bf16_t* Ab = (const bf16_t*)Ain;
    float4 rA[4];

    f32x4 acc[4][4];
#pragma unroll
    for (int mi = 0; mi < 4; ++mi)
#pragma unroll
        for (int ni = 0; ni < 4; ++ni) acc[mi][ni] = (f32x4){0.f, 0.f, 0.f, 0.f};

    // ---- prologue: stage tile 0 ----
    if (AF32) {
#pragma unroll
        for (int j = 0; j < 4; ++j)
            rA[j] = *reinterpret_cast<const float4*>(Af + (size_t)(m0 + a_r) * K + a_c + j * 4);
    } else {
#pragma unroll
        for (int i = 0; i < 2; ++i) {
            int c = wave * 2 + i;
            gld_lds16(Ab + (size_t)(m0 + c * 16 + srow) * K + scol, &Asmem[0][c * 512]);
        }
    }
#pragma unroll
    for (int i = 0; i < 2; ++i) {
        int c = wave * 2 + i;
        gld_lds16(W + (size_t)(n0 + c * 16 + srow) * K + scol, &Bsmem[0][c * 512]);
    }
    if (AF32) {
#pragma unroll
        for (int j = 0; j < 4; ++j) {
            uint2 u;
            u.x = cvt_pk_bf16(rA[j].x, rA[j].y);
            u.y = cvt_pk_bf16(rA[j].z, rA[j].w);
            *reinterpret_cast<uint2*>(&Asmem[0][a_r * 32 + a_c + j * 4]) = u;
        }
    }
    asm volatile("s_waitcnt vmcnt(0)" ::: "memory");
    __syncthreads();

    const int nk = K / 32;
    for (int t = 0; t < nk; ++t) {
        const int cur = t & 1, nxt = cur ^ 1;
        const int ktn = (t + 1) * 32;
        const bool more = (t + 1 < nk);
        if (more) {
            if (AF32) {
#pragma unroll
                for (int j = 0; j < 4; ++j)
                    rA[j] = *reinterpret_cast<const float4*>(Af + (size_t)(m0 + a_r) * K + ktn + a_c + j * 4);
            } else {
#pragma unroll
                for (int i = 0; i < 2; ++i) {
                    int c = wave * 2 + i;
                    gld_lds16(Ab + (size_t)(m0 + c * 16 + srow) * K + ktn + scol, &Asmem[nxt][c * 512]);
                }
            }
#pragma unroll
            for (int i = 0; i < 2; ++i) {
                int c = wave * 2 + i;
                gld_lds16(W + (size_t)(n0 + c * 16 + srow) * K + ktn + scol, &Bsmem[nxt][c * 512]);
            }
        }

        bf16x8 af[4], bfr[4];
#pragma unroll
        for (int mi = 0; mi < 4; ++mi)
            af[mi] = *reinterpret_cast<const bf16x8*>(&Asmem[cur][(wm * 64 + mi * 16 + lr) * 32 + lg * 8]);
#pragma unroll
        for (int ni = 0; ni < 4; ++ni)
            bfr[ni] = *reinterpret_cast<const bf16x8*>(&Bsmem[cur][(wn * 64 + ni * 16 + lr) * 32 + lg * 8]);
#pragma unroll
        for (int mi = 0; mi < 4; ++mi)
#pragma unroll
            for (int ni = 0; ni < 4; ++ni)
                acc[mi][ni] = __builtin_amdgcn_mfma_f32_16x16x32_bf16(af[mi], bfr[ni], acc[mi][ni], 0, 0, 0);

        if (more && AF32) {   // T14: convert+write AFTER compute (loads had MFMA phase to land)
#pragma unroll
            for (int j = 0; j < 4; ++j) {
                uint2 u;
                u.x = cvt_pk_bf16(rA[j].x, rA[j].y);
                u.y = cvt_pk_bf16(rA[j].z, rA[j].w);
                *reinterpret_cast<uint2*>(&Asmem[nxt][a_r * 32 + a_c + j * 4]) = u;
            }
        }
        asm volatile("s_waitcnt vmcnt(0)" ::: "memory");
        __syncthreads();
    }

#pragma unroll
    for (int mi = 0; mi < 4; ++mi) {
        int row = m0 + wm * 64 + mi * 16 + lg * 4;
#pragma unroll
        for (int ni = 0; ni < 4; ++ni) {
            int col = n0 + wn * 64 + ni * 16 + lr;
            float bv = bias[col];
            if (OMODE == 2) {
                union { bf16_t b[4]; uint2 u; } pq;
#pragma unroll
                for (int r = 0; r < 4; ++r) pq.b[r] = f2bf((acc[mi][ni][r] + bv) * scale);
                int b_ = row / S, s_ = row % S;
                size_t addr = (((size_t)b_ * NHEADS + (col >> 6)) * HDIM + (col & 63)) * (size_t)S + s_;
                *reinterpret_cast<uint2*>((bf16_t*)Cout + addr) = pq.u;
            } else {
#pragma unroll
                for (int r = 0; r < 4; ++r) {
                    float v = (acc[mi][ni][r] + bv) * scale;
                    if (OMODE == 1)
                        ((float*)Cout)[(size_t)(row + r) * N + col] = v;
                    else
                        ((bf16_t*)Cout)[(size_t)(row + r) * N + col] = f2bf(v);
                }
            }
        }
    }
}

// ---------------- flash attention (swapped-operand, dbuf KV, deferred max) ----------------
// grid: x = S/64 (q tiles), y = B*NHEADS. 256 threads = 4 waves, each 16 q rows.
// Qp/Kp: [B*S, DMODEL] bf16 (Q pre-scaled by 0.125*log2e). VtG: [B,H,D,S] bf16.
__global__ __launch_bounds__(256) void attn_kernel(const bf16_t* __restrict__ Qp,
                                                   const bf16_t* __restrict__ Kp,
                                                   const bf16_t* __restrict__ VtG,
                                                   bf16_t* __restrict__ AO, int S) {
    __shared__ bf16_t Ks[2][64 * 64];    // [key][dim], 16B blocks XOR-swizzled by (key&7)
    __shared__ bf16_t Vts[2][64 * 64];   // [dim][key], swizzled by (dim&7)
    const int tid = threadIdx.x;
    const int wave = tid >> 6, lane = tid & 63;
    const int lr = lane & 15, lg = lane >> 4;
    const int bh = blockIdx.y;
    const int b = bh >> 4, h = bh & 15;
    const int qt = blockIdx.x;
    const size_t base = ((size_t)b * S) * DMODEL + (size_t)h * HDIM;
    const size_t vbase = (size_t)bh * HDIM * (size_t)S;

    // Q fragment (B-operand): col=q=lr, k = lg*8+e (+32 for qf[1])
    const int qrow = qt * 64 + wave * 16 + lr;
    bf16x8 qf[2];
    qf[0] = *reinterpret_cast<const bf16x8*>(Qp + base + (size_t)qrow * DMODEL + lg * 8);
    qf[1] = *reinterpret_cast<const bf16x8*>(Qp + base + (size_t)qrow * DMODEL + 32 + lg * 8);

    f32x4 Oacc[4];
#pragma unroll
    for (int i = 0; i < 4; ++i) Oacc[i] = (f32x4){0.f, 0.f, 0.f, 0.f};
    float m_r = -1e30f, l_r = 0.f;

    const int r0 = tid >> 3;
    const int swz = ((tid & 7) ^ (r0 & 7)) * 8;

    const bf16_t* Kb = Kp + base;
    const bf16_t* Vb = VtG + vbase;

    // prologue: stage tile 0
    gld_lds16(Kb + (size_t)r0 * DMODEL + swz, &Ks[0][wave * 512]);
    gld_lds16(Kb + (size_t)(r0 + 32) * DMODEL + swz, &Ks[0][2048 + wave * 512]);
    gld_lds16(Vb + (size_t)r0 * S + swz, &Vts[0][wave * 512]);
    gld_lds16(Vb + (size_t)(r0 + 32) * S + swz, &Vts[0][2048 + wave * 512]);
    asm volatile("s_waitcnt vmcnt(0)" ::: "memory");
    __syncthreads();

    const int ntile = S / 64;
    for (int t = 0; t < ntile; ++t) {
        const int cur = t & 1, nxt = cur ^ 1;
        if (t + 1 < ntile) {
            const int kv = (t + 1) * 64;
            gld_lds16(Kb + (size_t)(kv + r0) * DMODEL + swz, &Ks[nxt][wave * 512]);
            gld_lds16(Kb + (size_t)(kv + r0 + 32) * DMODEL + swz, &Ks[nxt][2048 + wave * 512]);
            gld_lds16(Vb + (size_t)r0 * S + kv + swz, &Vts[nxt][wave * 512]);
            gld_lds16(Vb + (size_t)(r0 + 32) * S + kv + swz, &Vts[nxt][2048 + wave * 512]);
        }

        // S^T = mfma(A=K rows, B=Q): lane holds S[q=lr][key = nt*16 + lg*4 + r]
        f32x4 sc[4];
#pragma unroll
        for (int nt = 0; nt < 4; ++nt) {
            f32x4 a = (f32x4){0.f, 0.f, 0.f, 0.f};
#pragma unroll
            for (int kk = 0; kk < 2; ++kk) {
                bf16x8 kf = *reinterpret_cast<const bf16x8*>(
                    &Ks[cur][(nt * 16 + lr) * 64 + (((kk * 4 + lg) ^ (lr & 7)) * 8)]);
                a = __builtin_amdgcn_mfma_f32_16x16x32_bf16(kf, qf[kk], a, 0, 0, 0);
            }
            sc[nt] = a;
        }

        // row max (tree), cross-lane over the 4 lane-groups
        float mA = fmaxf(fmaxf(sc[0][0], sc[0][1]), fmaxf(sc[0][2], sc[0][3]));
        float mB = fmaxf(fmaxf(sc[1][0], sc[1][1]), fmaxf(sc[1][2], sc[1][3]));
        float mC = fmaxf(fmaxf(sc[2][0], sc[2][1]), fmaxf(sc[2][2], sc[2][3]));
        float mD = fmaxf(fmaxf(sc[3][0], sc[3][1]), fmaxf(sc[3][2], sc[3][3]));
        float mx = fmaxf(fmaxf(mA, mB), fmaxf(mC, mD));
        mx = fmaxf(mx, __shfl_xor(mx, 16, 64));
        mx = fmaxf(mx, __shfl_xor(mx, 32, 64));

        // T13 defer-max: only rescale when max grew by > 8 (log2 units)
        if (!__all(mx <= m_r + 8.f)) {
            float mnew = fmaxf(m_r, mx);
            float fsc = __builtin_amdgcn_exp2f(m_r - mnew);
            l_r *= fsc;
            m_r = mnew;
#pragma unroll
            for (int r = 0; r < 4; ++r) {
                float fr = __shfl(fsc, lg * 4 + r, 64);
#pragma unroll
                for (int nt2 = 0; nt2 < 4; ++nt2) Oacc[nt2][r] *= fr;
            }
        }

        float p[4][4];
        float s4[4];
#pragma unroll
        for (int nt = 0; nt < 4; ++nt) {
            p[nt][0] = __builtin_amdgcn_exp2f(sc[nt][0] - m_r);
            p[nt][1] = __builtin_amdgcn_exp2f(sc[nt][1] - m_r);
            p[nt][2] = __builtin_amdgcn_exp2f(sc[nt][2] - m_r);
            p[nt][3] = __builtin_amdgcn_exp2f(sc[nt][3] - m_r);
            s4[nt] = (p[nt][0] + p[nt][1]) + (p[nt][2] + p[nt][3]);
        }
        float ssum = (s4[0] + s4[1]) + (s4[2] + s4[3]);
        ssum += __shfl_xor(ssum, 16, 64);
        ssum += __shfl_xor(ssum, 32, 64);
        l_r += ssum;

        // pack P pairs (cvt_pk): w0[nt]=keys{16nt+4lg,+1}, w1[nt]={+2,+3}
        unsigned w0[4], w1[4];
#pragma unroll
        for (int nt = 0; nt < 4; ++nt) {
            w0[nt] = cvt_pk_bf16(p[nt][0], p[nt][1]);
            w1[nt] = cvt_pk_bf16(p[nt][2], p[nt][3]);
        }
        // redistribute to A-fragment (verified r2 mapping): lane needs keys 32kk+8lg+{0..7}
        // u[0]=w0[2kk+hi]@s0, u[1]=w1[2kk+hi]@s0, u[2]=w0[2kk+hi]@s1, u[3]=w1[2kk+hi]@s1
        const int s0 = lr + ((lg & 1) << 5);
        const int s1 = s0 + 16;
        const int hi = lg >> 1;
        bf16x8 pa[2];
#pragma unroll
        for (int kk = 0; kk < 2; ++kk) {
            unsigned a0 = (unsigned)__shfl((int)w0[2 * kk], s0, 64);
            unsigned b0 = (unsigned)__shfl((int)w0[2 * kk + 1], s0, 64);
            unsigned a1 = (unsigned)__shfl((int)w1[2 * kk], s0, 64);
            unsigned b1 = (unsigned)__shfl((int)w1[2 * kk + 1], s0, 64);
            unsigned a2 = (unsigned)__shfl((int)w0[2 * kk], s1, 64);
            unsigned b2 = (unsigned)__shfl((int)w0[2 * kk + 1], s1, 64);
            unsigned a3 = (unsigned)__shfl((int)w1[2 * kk], s1, 64);
            unsigned b3 = (unsigned)__shfl((int)w1[2 * kk + 1], s1, 64);
            union { unsigned u[4]; bf16x8 v; } pu;
            pu.u[0] = hi ? b0 : a0;
            pu.u[1] = hi ? b1 : a1;
            pu.u[2] = hi ? b2 : a2;
            pu.u[3] = hi ? b3 : a3;
            pa[kk] = pu.v;
        }

        // PV: O[q][d] += P V
#pragma unroll
        for (int nt2 = 0; nt2 < 4; ++nt2) {
#pragma unroll
            for (int kk = 0; kk < 2; ++kk) {
                bf16x8 vf = *reinterpret_cast<const bf16x8*>(
                    &Vts[cur][(nt2 * 16 + lr) * 64 + (((kk * 4 + lg) ^ (lr & 7)) * 8)]);
                Oacc[nt2] = __builtin_amdgcn_mfma_f32_16x16x32_bf16(pa[kk], vf, Oacc[nt2], 0, 0, 0);
            }
        }

        asm volatile("s_waitcnt vmcnt(0)" ::: "memory");
        __syncthreads();
    }

    // epilogue: rows q = lg*4+r, cols d = nt2*16+lr
#pragma unroll
    for (int r = 0; r < 4; ++r) {
        float lsum = __shfl(l_r, lg * 4 + r, 64);
        float inv = 1.f / lsum;
        int row = qt * 64 + wave * 16 + lg * 4 + r;
#pragma unroll
        for (int nt2 = 0; nt2 < 4; ++nt2)
            AO[base + (size_t)row * DMODEL + nt2 * 16 + lr] = f2bf(Oacc[nt2][r] * inv);
    }
}

extern "C" void kernel_launch(void* const* d_in, const int* in_sizes, int n_in,
                              void* d_out, int out_size, void* d_ws, size_t ws_size,
                              hipStream_t stream) {
    const float* q  = (const float*)d_in[0];
    const float* k  = (const float*)d_in[1];
    const float* v  = (const float*)d_in[2];
    const float* Wq = (const float*)d_in[3];
    const float* bq = (const float*)d_in[4];
    const float* Wk = (const float*)d_in[5];
    const float* bk = (const float*)d_in[6];
    const float* Wv = (const float*)d_in[7];
    const float* bv = (const float*)d_in[8];
    const float* Wo = (const float*)d_in[9];
    const float* bo = (const float*)d_in[10];

    const int M = in_sizes[0] / DMODEL;   // B*S
    const int S = 2048;
    const int B = M / S;

    bf16_t* ws  = (bf16_t*)d_ws;
    const size_t WSZ = (size_t)DMODEL * DMODEL;
    const size_t MSZ = (size_t)M * DMODEL;
    bf16_t* Wqb = ws;
    bf16_t* Wkb = Wqb + WSZ;
    bf16_t* Wvb = Wkb + WSZ;
    bf16_t* Wob = Wvb + WSZ;
    bf16_t* Qp  = Wob + WSZ;
    bf16_t* Kp  = Qp + MSZ;
    bf16_t* VtG = Kp + MSZ;
    bf16_t* AO  = VtG + MSZ;

    cast4<<<dim3(1024, 4), 256, 0, stream>>>(Wq, Wk, Wv, Wo, ws, DMODEL * DMODEL);

    const float qscale = 0.125f * 1.44269504088896f;   // 1/sqrt(64) * log2(e)
    dim3 gg(M / 128, DMODEL / 128);
    gemm_bt<1, 0><<<gg, 256, 0, stream>>>(q, Wqb, bq, Qp, M, DMODEL, DMODEL, qscale, S);
    gemm_bt<1, 0><<<gg, 256, 0, stream>>>(k, Wkb, bk, Kp, M, DMODEL, DMODEL, 1.0f, S);
    gemm_bt<1, 2><<<gg, 256, 0, stream>>>(v, Wvb, bv, VtG, M, DMODEL, DMODEL, 1.0f, S);

    attn_kernel<<<dim3(S / 64, B * NHEADS), 256, 0, stream>>>(Qp, Kp, VtG, AO, S);

    gemm_bt<0, 1><<<gg, 256, 0, stream>>>(AO, Wob, bo, d_out, M, DMODEL, DMODEL, 1.0f, S);
}

// Round 5
// 291.835 us; speedup vs baseline: 1.6307x; 1.0079x over previous
//
#include <hip/hip_runtime.h>
#include <hip/hip_bf16.h>

#define DMODEL 1024
#define NHEADS 16
#define HDIM 64

typedef __bf16 bf16_t;
typedef __bf16 bf16x8 __attribute__((ext_vector_type(8)));
typedef float  f32x4  __attribute__((ext_vector_type(4)));

__device__ __forceinline__ bf16_t f2bf(float f) {
    unsigned int u = __builtin_bit_cast(unsigned int, f);
    u += 0x7FFF + ((u >> 16) & 1);           // RNE
    unsigned short h = (unsigned short)(u >> 16);
    return __builtin_bit_cast(bf16_t, h);
}

__device__ __forceinline__ unsigned cvt_pk_bf16(float lo, float hi) {
    unsigned r;
    asm("v_cvt_pk_bf16_f32 %0, %1, %2" : "=v"(r) : "v"(lo), "v"(hi));
    return r;
}

__device__ __forceinline__ void gld_lds16(const bf16_t* g, bf16_t* l) {
    __builtin_amdgcn_global_load_lds(
        (const __attribute__((address_space(1))) unsigned int*)g,
        (__attribute__((address_space(3))) unsigned int*)l, 16, 0, 0);
}

// ---------------- fp32 -> bf16 cast: 4 weight matrices, one launch ----------------
__global__ __launch_bounds__(256) void cast4(const float* __restrict__ s0,
                                             const float* __restrict__ s1,
                                             const float* __restrict__ s2,
                                             const float* __restrict__ s3,
                                             bf16_t* __restrict__ d, int n) {
    int y = blockIdx.y;
    const float* s = (y == 0) ? s0 : (y == 1) ? s1 : (y == 2) ? s2 : s3;
    bf16_t* dst = d + (size_t)y * n;
    int i = blockIdx.x * blockDim.x + threadIdx.x;
    int stride = gridDim.x * blockDim.x;
    for (int idx = i * 4; idx < n; idx += stride * 4) {
        float4 v = *reinterpret_cast<const float4*>(s + idx);
        uint2 u;
        u.x = cvt_pk_bf16(v.x, v.y);
        u.y = cvt_pk_bf16(v.z, v.w);
        *reinterpret_cast<uint2*>(dst + idx) = u;
    }
}

// ---------------- GEMM: C[m,n] = (sum_k A[m,k]*W[n,k] + bias[n]) * scale ----------------
template <int AF32, int OMODE>
__global__ __launch_bounds__(256) void gemm_bt(const void* __restrict__ Ain,
                                               const bf16_t* __restrict__ W,
                                               const float* __restrict__ bias,
                                               void* __restrict__ Cout,
                                               int M, int N, int K, float scale, int S) {
    __shared__ bf16_t Asmem[2][128 * 32];
    __shared__ bf16_t Bsmem[2][128 * 32];
    const int m0 = blockIdx.x * 128;
    const int n0 = blockIdx.y * 128;
    const int tid = threadIdx.x;
    const int wave = tid >> 6, lane = tid & 63;
    const int wm = wave >> 1, wn = wave & 1;
    const int lr = lane & 15, lg = lane >> 4;
    const int srow = lane >> 2, scol = (lane & 3) * 8;   // gld_lds geometry
    const int a_r = tid >> 1, a_c = (tid & 1) * 16;      // fp32-A geometry

    const float* Af = (const float*)Ain;
    const bf16_t* Ab = (const bf16_t*)Ain;
    float4 rA[4];

    f32x4 acc[4][4];
#pragma unroll
    for (int mi = 0; mi < 4; ++mi)
#pragma unroll
        for (int ni = 0; ni < 4; ++ni) acc[mi][ni] = (f32x4){0.f, 0.f, 0.f, 0.f};

    // ---- prologue: stage tile 0 ----
    if (AF32) {
#pragma unroll
        for (int j = 0; j < 4; ++j)
            rA[j] = *reinterpret_cast<const float4*>(Af + (size_t)(m0 + a_r) * K + a_c + j * 4);
    } else {
#pragma unroll
        for (int i = 0; i < 2; ++i) {
            int c = wave * 2 + i;
            gld_lds16(Ab + (size_t)(m0 + c * 16 + srow) * K + scol, &Asmem[0][c * 512]);
        }
    }
#pragma unroll
    for (int i = 0; i < 2; ++i) {
        int c = wave * 2 + i;
        gld_lds16(W + (size_t)(n0 + c * 16 + srow) * K + scol, &Bsmem[0][c * 512]);
    }
    if (AF32) {
#pragma unroll
        for (int j = 0; j < 4; ++j) {
            uint2 u;
            u.x = cvt_pk_bf16(rA[j].x, rA[j].y);
            u.y = cvt_pk_bf16(rA[j].z, rA[j].w);
            *reinterpret_cast<uint2*>(&Asmem[0][a_r * 32 + a_c + j * 4]) = u;
        }
    }
    asm volatile("s_waitcnt vmcnt(0)" ::: "memory");
    __syncthreads();

    const int nk = K / 32;
    for (int t = 0; t < nk; ++t) {
        const int cur = t & 1, nxt = cur ^ 1;
        const int ktn = (t + 1) * 32;
        const bool more = (t + 1 < nk);
        if (more) {
            if (AF32) {
#pragma unroll
                for (int j = 0; j < 4; ++j)
                    rA[j] = *reinterpret_cast<const float4*>(Af + (size_t)(m0 + a_r) * K + ktn + a_c + j * 4);
            } else {
#pragma unroll
                for (int i = 0; i < 2; ++i) {
                    int c = wave * 2 + i;
                    gld_lds16(Ab + (size_t)(m0 + c * 16 + srow) * K + ktn + scol, &Asmem[nxt][c * 512]);
                }
            }
#pragma unroll
            for (int i = 0; i < 2; ++i) {
                int c = wave * 2 + i;
                gld_lds16(W + (size_t)(n0 + c * 16 + srow) * K + ktn + scol, &Bsmem[nxt][c * 512]);
            }
        }

        bf16x8 af[4], bfr[4];
#pragma unroll
        for (int mi = 0; mi < 4; ++mi)
            af[mi] = *reinterpret_cast<const bf16x8*>(&Asmem[cur][(wm * 64 + mi * 16 + lr) * 32 + lg * 8]);
#pragma unroll
        for (int ni = 0; ni < 4; ++ni)
            bfr[ni] = *reinterpret_cast<const bf16x8*>(&Bsmem[cur][(wn * 64 + ni * 16 + lr) * 32 + lg * 8]);
#pragma unroll
        for (int mi = 0; mi < 4; ++mi)
#pragma unroll
            for (int ni = 0; ni < 4; ++ni)
                acc[mi][ni] = __builtin_amdgcn_mfma_f32_16x16x32_bf16(af[mi], bfr[ni], acc[mi][ni], 0, 0, 0);

        if (more && AF32) {   // T14: convert+write AFTER compute
#pragma unroll
            for (int j = 0; j < 4; ++j) {
                uint2 u;
                u.x = cvt_pk_bf16(rA[j].x, rA[j].y);
                u.y = cvt_pk_bf16(rA[j].z, rA[j].w);
                *reinterpret_cast<uint2*>(&Asmem[nxt][a_r * 32 + a_c + j * 4]) = u;
            }
        }
        asm volatile("s_waitcnt vmcnt(0)" ::: "memory");
        __syncthreads();
    }

#pragma unroll
    for (int mi = 0; mi < 4; ++mi) {
        int row = m0 + wm * 64 + mi * 16 + lg * 4;
#pragma unroll
        for (int ni = 0; ni < 4; ++ni) {
            int col = n0 + wn * 64 + ni * 16 + lr;
            float bv = bias[col];
            if (OMODE == 2) {
                union { bf16_t b[4]; uint2 u; } pq;
#pragma unroll
                for (int r = 0; r < 4; ++r) pq.b[r] = f2bf((acc[mi][ni][r] + bv) * scale);
                int b_ = row / S, s_ = row % S;
                size_t addr = (((size_t)b_ * NHEADS + (col >> 6)) * HDIM + (col & 63)) * (size_t)S + s_;
                *reinterpret_cast<uint2*>((bf16_t*)Cout + addr) = pq.u;
            } else {
#pragma unroll
                for (int r = 0; r < 4; ++r) {
                    float v = (acc[mi][ni][r] + bv) * scale;
                    if (OMODE == 1)
                        ((float*)Cout)[(size_t)(row + r) * N + col] = v;
                    else
                        ((bf16_t*)Cout)[(size_t)(row + r) * N + col] = f2bf(v);
                }
            }
        }
    }
}

// ---------------- flash attention: QK^T pipelined one tile ahead of softmax/PV ----------------
// grid: x = S/64 (q tiles), y = B*NHEADS. 256 threads = 4 waves, each 16 q rows.
// Qp/Kp: [B*S, DMODEL] bf16 (Q pre-scaled by 0.125*log2e). VtG: [B,H,D,S] bf16.
__global__ __launch_bounds__(256) void attn_kernel(const bf16_t* __restrict__ Qp,
                                                   const bf16_t* __restrict__ Kp,
                                                   const bf16_t* __restrict__ VtG,
                                                   bf16_t* __restrict__ AO, int S) {
    __shared__ bf16_t KsA[64 * 64], KsB[64 * 64];   // K(j) -> Ks[j&1], 16B blocks XOR-swz (key&7)
    __shared__ bf16_t VtA[64 * 64], VtB[64 * 64];   // V(j) -> Vt[j&1], swz (dim&7)
    const int tid = threadIdx.x;
    const int wave = tid >> 6, lane = tid & 63;
    const int lr = lane & 15, lg = lane >> 4;
    const int bh = blockIdx.y;
    const int b = bh >> 4, h = bh & 15;
    const int qt = blockIdx.x;
    const size_t base = ((size_t)b * S) * DMODEL + (size_t)h * HDIM;
    const size_t vbase = (size_t)bh * HDIM * (size_t)S;

    // Q fragment (B-operand): col=q=lr, k = lg*8+e (+32 for qf[1])
    const int qrow = qt * 64 + wave * 16 + lr;
    bf16x8 qf[2];
    qf[0] = *reinterpret_cast<const bf16x8*>(Qp + base + (size_t)qrow * DMODEL + lg * 8);
    qf[1] = *reinterpret_cast<const bf16x8*>(Qp + base + (size_t)qrow * DMODEL + 32 + lg * 8);

    f32x4 Oacc[4];
#pragma unroll
    for (int i = 0; i < 4; ++i) Oacc[i] = (f32x4){0.f, 0.f, 0.f, 0.f};
    float m_r = -1e30f, l_r = 0.f;

    const int r0 = tid >> 3;
    const int swz = ((tid & 7) ^ (r0 & 7)) * 8;
    const bf16_t* Kb = Kp + base;
    const bf16_t* Vb = VtG + vbase;

    auto stageK = [&](int kv, bf16_t* buf) {
        gld_lds16(Kb + (size_t)(kv + r0) * DMODEL + swz, buf + wave * 512);
        gld_lds16(Kb + (size_t)(kv + r0 + 32) * DMODEL + swz, buf + 2048 + wave * 512);
    };
    auto stageV = [&](int kv, bf16_t* buf) {
        gld_lds16(Vb + (size_t)r0 * S + kv + swz, buf + wave * 512);
        gld_lds16(Vb + (size_t)(r0 + 32) * S + kv + swz, buf + 2048 + wave * 512);
    };
    // S^T = mfma(A=K rows, B=Q): lane holds S[q=lr][key = nt*16 + lg*4 + r]
    auto qk = [&](const bf16_t* Ksb, f32x4 (&sc)[4]) {
        __builtin_amdgcn_s_setprio(1);
#pragma unroll
        for (int nt = 0; nt < 4; ++nt) {
            f32x4 a = (f32x4){0.f, 0.f, 0.f, 0.f};
#pragma unroll
            for (int kk = 0; kk < 2; ++kk) {
                bf16x8 kf = *reinterpret_cast<const bf16x8*>(
                    &Ksb[(nt * 16 + lr) * 64 + (((kk * 4 + lg) ^ (lr & 7)) * 8)]);
                a = __builtin_amdgcn_mfma_f32_16x16x32_bf16(kf, qf[kk], a, 0, 0, 0);
            }
            sc[nt] = a;
        }
        __builtin_amdgcn_s_setprio(0);
    };
    auto smaxpv = [&](f32x4 (&sc)[4], const bf16_t* Vtb) {
        // row max (tree), cross-lane over the 4 lane-groups
        float mA = fmaxf(fmaxf(sc[0][0], sc[0][1]), fmaxf(sc[0][2], sc[0][3]));
        float mB = fmaxf(fmaxf(sc[1][0], sc[1][1]), fmaxf(sc[1][2], sc[1][3]));
        float mC = fmaxf(fmaxf(sc[2][0], sc[2][1]), fmaxf(sc[2][2], sc[2][3]));
        float mD = fmaxf(fmaxf(sc[3][0], sc[3][1]), fmaxf(sc[3][2], sc[3][3]));
        float mx = fmaxf(fmaxf(mA, mB), fmaxf(mC, mD));
        mx = fmaxf(mx, __shfl_xor(mx, 16, 64));
        mx = fmaxf(mx, __shfl_xor(mx, 32, 64));

        // T13 defer-max: only rescale when max grew by > 8 (log2 units)
        if (!__all(mx <= m_r + 8.f)) {
            float mnew = fmaxf(m_r, mx);
            float fsc = __builtin_amdgcn_exp2f(m_r - mnew);
            l_r *= fsc;
            m_r = mnew;
#pragma unroll
            for (int r = 0; r < 4; ++r) {
                float fr = __shfl(fsc, lg * 4 + r, 64);
#pragma unroll
                for (int nt2 = 0; nt2 < 4; ++nt2) Oacc[nt2][r] *= fr;
            }
        }

        float p[4][4];
        float s4[4];
#pragma unroll
        for (int nt = 0; nt < 4; ++nt) {
            p[nt][0] = __builtin_amdgcn_exp2f(sc[nt][0] - m_r);
            p[nt][1] = __builtin_amdgcn_exp2f(sc[nt][1] - m_r);
            p[nt][2] = __builtin_amdgcn_exp2f(sc[nt][2] - m_r);
            p[nt][3] = __builtin_amdgcn_exp2f(sc[nt][3] - m_r);
            s4[nt] = (p[nt][0] + p[nt][1]) + (p[nt][2] + p[nt][3]);
        }
        float ssum = (s4[0] + s4[1]) + (s4[2] + s4[3]);
        ssum += __shfl_xor(ssum, 16, 64);
        ssum += __shfl_xor(ssum, 32, 64);
        l_r += ssum;

        // pack P pairs: w0[nt]=keys{16nt+4lg,+1}, w1[nt]={+2,+3}
        unsigned w0[4], w1[4];
#pragma unroll
        for (int nt = 0; nt < 4; ++nt) {
            w0[nt] = cvt_pk_bf16(p[nt][0], p[nt][1]);
            w1[nt] = cvt_pk_bf16(p[nt][2], p[nt][3]);
        }
        // redistribute to A-fragment (verified r2/r4 mapping): lane needs keys 32kk+8lg+{0..7}
        const int s0 = lr + ((lg & 1) << 5);
        const int s1 = s0 + 16;
        const int hi = lg >> 1;
        bf16x8 pa[2];
#pragma unroll
        for (int kk = 0; kk < 2; ++kk) {
            unsigned a0 = (unsigned)__shfl((int)w0[2 * kk], s0, 64);
            unsigned b0 = (unsigned)__shfl((int)w0[2 * kk + 1], s0, 64);
            unsigned a1 = (unsigned)__shfl((int)w1[2 * kk], s0, 64);
            unsigned b1 = (unsigned)__shfl((int)w1[2 * kk + 1], s0, 64);
            unsigned a2 = (unsigned)__shfl((int)w0[2 * kk], s1, 64);
            unsigned b2 = (unsigned)__shfl((int)w0[2 * kk + 1], s1, 64);
            unsigned a3 = (unsigned)__shfl((int)w1[2 * kk], s1, 64);
            unsigned b3 = (unsigned)__shfl((int)w1[2 * kk + 1], s1, 64);
            union { unsigned u[4]; bf16x8 v; } pu;
            pu.u[0] = hi ? b0 : a0;
            pu.u[1] = hi ? b1 : a1;
            pu.u[2] = hi ? b2 : a2;
            pu.u[3] = hi ? b3 : a3;
            pa[kk] = pu.v;
        }

        // PV: O[q][d] += P V
        __builtin_amdgcn_s_setprio(1);
#pragma unroll
        for (int nt2 = 0; nt2 < 4; ++nt2) {
#pragma unroll
            for (int kk = 0; kk < 2; ++kk) {
                bf16x8 vf = *reinterpret_cast<const bf16x8*>(
                    &Vtb[(nt2 * 16 + lr) * 64 + (((kk * 4 + lg) ^ (lr & 7)) * 8)]);
                Oacc[nt2] = __builtin_amdgcn_mfma_f32_16x16x32_bf16(pa[kk], vf, Oacc[nt2], 0, 0, 0);
            }
        }
        __builtin_amdgcn_s_setprio(0);
    };

    // ---- prologue: K(0)->KsA, V(0)->VtA, K(1)->KsB; QK(0) ----
    stageK(0, KsA);
    stageV(0, VtA);
    stageK(64, KsB);
    __syncthreads();                 // implicit vmcnt(0)+lgkmcnt(0) drain
    f32x4 scA[4], scB[4];
    qk(KsA, scA);

    const int NT = S / 64;           // 32 (even)
    for (int t = 0; t < NT; t += 2) {
        // ---- even half: process tile t (scA, VtA); QK(t+1) from KsB ----
        __syncthreads();             // drains K(t+1)[prev], V(t)[prev] staging; protects buffers
        if (t + 2 < NT) stageK((t + 2) * 64, KsA);
        if (t + 1 < NT) stageV((t + 1) * 64, VtB);
        if (t + 1 < NT) qk(KsB, scB);
        smaxpv(scA, VtA);
        // ---- odd half: process tile t+1 (scB, VtB); QK(t+2) from KsA ----
        __syncthreads();
        if (t + 3 < NT) stageK((t + 3) * 64, KsB);
        if (t + 2 < NT) stageV((t + 2) * 64, VtA);
        if (t + 2 < NT) qk(KsA, scA);
        smaxpv(scB, VtB);
    }

    // epilogue: rows q = lg*4+r, cols d = nt2*16+lr
#pragma unroll
    for (int r = 0; r < 4; ++r) {
        float lsum = __shfl(l_r, lg * 4 + r, 64);
        float inv = 1.f / lsum;
        int row = qt * 64 + wave * 16 + lg * 4 + r;
#pragma unroll
        for (int nt2 = 0; nt2 < 4; ++nt2)
            AO[base + (size_t)row * DMODEL + nt2 * 16 + lr] = f2bf(Oacc[nt2][r] * inv);
    }
}

extern "C" void kernel_launch(void* const* d_in, const int* in_sizes, int n_in,
                              void* d_out, int out_size, void* d_ws, size_t ws_size,
                              hipStream_t stream) {
    const float* q  = (const float*)d_in[0];
    const float* k  = (const float*)d_in[1];
    const float* v  = (const float*)d_in[2];
    const float* Wq = (const float*)d_in[3];
    const float* bq = (const float*)d_in[4];
    const float* Wk = (const float*)d_in[5];
    const float* bk = (const float*)d_in[6];
    const float* Wv = (const float*)d_in[7];
    const float* bv = (const float*)d_in[8];
    const float* Wo = (const float*)d_in[9];
    const float* bo = (const float*)d_in[10];

    const int M = in_sizes[0] / DMODEL;   // B*S
    const int S = 2048;
    const int B = M / S;

    bf16_t* ws  = (bf16_t*)d_ws;
    const size_t WSZ = (size_t)DMODEL * DMODEL;
    const size_t MSZ = (size_t)M * DMODEL;
    bf16_t* Wqb = ws;
    bf16_t* Wkb = Wqb + WSZ;
    bf16_t* Wvb = Wkb + WSZ;
    bf16_t* Wob = Wvb + WSZ;
    bf16_t* Qp  = Wob + WSZ;
    bf16_t* Kp  = Qp + MSZ;
    bf16_t* VtG = Kp + MSZ;
    bf16_t* AO  = VtG + MSZ;

    cast4<<<dim3(1024, 4), 256, 0, stream>>>(Wq, Wk, Wv, Wo, ws, DMODEL * DMODEL);

    const float qscale = 0.125f * 1.44269504088896f;   // 1/sqrt(64) * log2(e)
    dim3 gg(M / 128, DMODEL / 128);
    gemm_bt<1, 0><<<gg, 256, 0, stream>>>(q, Wqb, bq, Qp, M, DMODEL, DMODEL, qscale, S);
    gemm_bt<1, 0><<<gg, 256, 0, stream>>>(k, Wkb, bk, Kp, M, DMODEL, DMODEL, 1.0f, S);
    gemm_bt<1, 2><<<gg, 256, 0, stream>>>(v, Wvb, bv, VtG, M, DMODEL, DMODEL, 1.0f, S);

    attn_kernel<<<dim3(S / 64, B * NHEADS), 256, 0, stream>>>(Qp, Kp, VtG, AO, S);

    gemm_bt<0, 1><<<gg, 256, 0, stream>>>(AO, Wob, bo, d_out, M, DMODEL, DMODEL, 1.0f, S);
}

// Round 6
// 254.662 us; speedup vs baseline: 1.8688x; 1.1460x over previous
//
#include <hip/hip_runtime.h>
#include <hip/hip_bf16.h>

#define DMODEL 1024
#define NHEADS 16
#define HDIM 64

typedef __bf16 bf16_t;
typedef __bf16 bf16x8 __attribute__((ext_vector_type(8)));
typedef float  f32x4  __attribute__((ext_vector_type(4)));
typedef float  f32x16 __attribute__((ext_vector_type(16)));

__device__ __forceinline__ bf16_t f2bf(float f) {
    unsigned int u = __builtin_bit_cast(unsigned int, f);
    u += 0x7FFF + ((u >> 16) & 1);           // RNE
    unsigned short h = (unsigned short)(u >> 16);
    return __builtin_bit_cast(bf16_t, h);
}

__device__ __forceinline__ unsigned cvt_pk_bf16(float lo, float hi) {
    unsigned r;
    asm("v_cvt_pk_bf16_f32 %0, %1, %2" : "=v"(r) : "v"(lo), "v"(hi));
    return r;
}

__device__ __forceinline__ void gld_lds16(const bf16_t* g, bf16_t* l) {
    __builtin_amdgcn_global_load_lds(
        (const __attribute__((address_space(1))) unsigned int*)g,
        (__attribute__((address_space(3))) unsigned int*)l, 16, 0, 0);
}

// ---------------- fp32 -> bf16 cast: 4 weight matrices, one launch ----------------
__global__ __launch_bounds__(256) void cast4(const float* __restrict__ s0,
                                             const float* __restrict__ s1,
                                             const float* __restrict__ s2,
                                             const float* __restrict__ s3,
                                             bf16_t* __restrict__ d, int n) {
    int y = blockIdx.y;
    const float* s = (y == 0) ? s0 : (y == 1) ? s1 : (y == 2) ? s2 : s3;
    bf16_t* dst = d + (size_t)y * n;
    int i = blockIdx.x * blockDim.x + threadIdx.x;
    int stride = gridDim.x * blockDim.x;
    for (int idx = i * 4; idx < n; idx += stride * 4) {
        float4 v = *reinterpret_cast<const float4*>(s + idx);
        uint2 u;
        u.x = cvt_pk_bf16(v.x, v.y);
        u.y = cvt_pk_bf16(v.z, v.w);
        *reinterpret_cast<uint2*>(dst + idx) = u;
    }
}

// ---------------- GEMM: C[m,n] = (sum_k A[m,k]*W[n,k] + bias[n]) * scale ----------------
template <int AF32, int OMODE>
__global__ __launch_bounds__(256) void gemm_bt(const void* __restrict__ Ain,
                                               const bf16_t* __restrict__ W,
                                               const float* __restrict__ bias,
                                               void* __restrict__ Cout,
                                               int M, int N, int K, float scale, int S) {
    __shared__ bf16_t Asmem[2][128 * 32];
    __shared__ bf16_t Bsmem[2][128 * 32];
    const int m0 = blockIdx.x * 128;
    const int n0 = blockIdx.y * 128;
    const int tid = threadIdx.x;
    const int wave = tid >> 6, lane = tid & 63;
    const int wm = wave >> 1, wn = wave & 1;
    const int lr = lane & 15, lg = lane >> 4;
    const int srow = lane >> 2, scol = (lane & 3) * 8;   // gld_lds geometry
    const int a_r = tid >> 1, a_c = (tid & 1) * 16;      // fp32-A geometry

    const float* Af = (const float*)Ain;
    const bf16_t* Ab = (const bf16_t*)Ain;
    float4 rA[4];

    f32x4 acc[4][4];
#pragma unroll
    for (int mi = 0; mi < 4; ++mi)
#pragma unroll
        for (int ni = 0; ni < 4; ++ni) acc[mi][ni] = (f32x4){0.f, 0.f, 0.f, 0.f};

    // ---- prologue: stage tile 0 ----
    if (AF32) {
#pragma unroll
        for (int j = 0; j < 4; ++j)
            rA[j] = *reinterpret_cast<const float4*>(Af + (size_t)(m0 + a_r) * K + a_c + j * 4);
    } else {
#pragma unroll
        for (int i = 0; i < 2; ++i) {
            int c = wave * 2 + i;
            gld_lds16(Ab + (size_t)(m0 + c * 16 + srow) * K + scol, &Asmem[0][c * 512]);
        }
    }
#pragma unroll
    for (int i = 0; i < 2; ++i) {
        int c = wave * 2 + i;
        gld_lds16(W + (size_t)(n0 + c * 16 + srow) * K + scol, &Bsmem[0][c * 512]);
    }
    if (AF32) {
#pragma unroll
        for (int j = 0; j < 4; ++j) {
            uint2 u;
            u.x = cvt_pk_bf16(rA[j].x, rA[j].y);
            u.y = cvt_pk_bf16(rA[j].z, rA[j].w);
            *reinterpret_cast<uint2*>(&Asmem[0][a_r * 32 + a_c + j * 4]) = u;
        }
    }
    asm volatile("s_waitcnt vmcnt(0)" ::: "memory");
    __syncthreads();

    const int nk = K / 32;
    for (int t = 0; t < nk; ++t) {
        const int cur = t & 1, nxt = cur ^ 1;
        const int ktn = (t + 1) * 32;
        const bool more = (t + 1 < nk);
        if (more) {
            if (AF32) {
#pragma unroll
                for (int j = 0; j < 4; ++j)
                    rA[j] = *reinterpret_cast<const float4*>(Af + (size_t)(m0 + a_r) * K + ktn + a_c + j * 4);
            } else {
#pragma unroll
                for (int i = 0; i < 2; ++i) {
                    int c = wave * 2 + i;
                    gld_lds16(Ab + (size_t)(m0 + c * 16 + srow) * K + ktn + scol, &Asmem[nxt][c * 512]);
                }
            }
#pragma unroll
            for (int i = 0; i < 2; ++i) {
                int c = wave * 2 + i;
                gld_lds16(W + (size_t)(n0 + c * 16 + srow) * K + ktn + scol, &Bsmem[nxt][c * 512]);
            }
        }

        bf16x8 af[4], bfr[4];
#pragma unroll
        for (int mi = 0; mi < 4; ++mi)
            af[mi] = *reinterpret_cast<const bf16x8*>(&Asmem[cur][(wm * 64 + mi * 16 + lr) * 32 + lg * 8]);
#pragma unroll
        for (int ni = 0; ni < 4; ++ni)
            bfr[ni] = *reinterpret_cast<const bf16x8*>(&Bsmem[cur][(wn * 64 + ni * 16 + lr) * 32 + lg * 8]);
#pragma unroll
        for (int mi = 0; mi < 4; ++mi)
#pragma unroll
            for (int ni = 0; ni < 4; ++ni)
                acc[mi][ni] = __builtin_amdgcn_mfma_f32_16x16x32_bf16(af[mi], bfr[ni], acc[mi][ni], 0, 0, 0);

        if (more && AF32) {   // T14: convert+write AFTER compute
#pragma unroll
            for (int j = 0; j < 4; ++j) {
                uint2 u;
                u.x = cvt_pk_bf16(rA[j].x, rA[j].y);
                u.y = cvt_pk_bf16(rA[j].z, rA[j].w);
                *reinterpret_cast<uint2*>(&Asmem[nxt][a_r * 32 + a_c + j * 4]) = u;
            }
        }
        asm volatile("s_waitcnt vmcnt(0)" ::: "memory");
        __syncthreads();
    }

#pragma unroll
    for (int mi = 0; mi < 4; ++mi) {
        int row = m0 + wm * 64 + mi * 16 + lg * 4;
#pragma unroll
        for (int ni = 0; ni < 4; ++ni) {
            int col = n0 + wn * 64 + ni * 16 + lr;
            float bv = bias[col];
            if (OMODE == 2) {
                union { bf16_t b[4]; uint2 u; } pq;
#pragma unroll
                for (int r = 0; r < 4; ++r) pq.b[r] = f2bf((acc[mi][ni][r] + bv) * scale);
                int b_ = row / S, s_ = row % S;
                size_t addr = (((size_t)b_ * NHEADS + (col >> 6)) * HDIM + (col & 63)) * (size_t)S + s_;
                *reinterpret_cast<uint2*>((bf16_t*)Cout + addr) = pq.u;
            } else {
#pragma unroll
                for (int r = 0; r < 4; ++r) {
                    float v = (acc[mi][ni][r] + bv) * scale;
                    if (OMODE == 1)
                        ((float*)Cout)[(size_t)(row + r) * N + col] = v;
                    else
                        ((bf16_t*)Cout)[(size_t)(row + r) * N + col] = f2bf(v);
                }
            }
        }
    }
}

// ---------------- flash attention: 32x32 swapped-operand, lane-owns-q-row ----------------
// grid: x = S/128 (q tiles of 128), y = B*NHEADS. 256 threads = 4 waves, each 32 q rows.
// Qp/Kp: [B*S, DMODEL] bf16 (Q pre-scaled by 0.125*log2e). VtG: [B,H,D,S] bf16.
//
// MFMA 32x32x16 fragment layouts (m74/m101-verified C/D; A/B mirror verified 16x16):
//   A: lane l holds A[row=l&31][k=(l>>5)*8+e]   B: lane holds B[k=(l>>5)*8+e][col=l&31]
//   C/D: lane holds D[row=(reg&3)+8*(reg>>2)+4*(l>>5)][col=l&31]
// QK^T swapped: T = mfma(K, Q): T[key][q], lane owns q = l&31 (hi=l>>5 selects key nibble).
// PV swapped:   O^T = mfma(V^T, P^T): O^T[d][q], same lane-owns-q -> all softmax state in-lane.
__global__ __launch_bounds__(256, 4) void attn_kernel(const bf16_t* __restrict__ Qp,
                                                      const bf16_t* __restrict__ Kp,
                                                      const bf16_t* __restrict__ VtG,
                                                      bf16_t* __restrict__ AO, int S) {
    __shared__ bf16_t KsA[64 * 64], KsB[64 * 64];   // [key][dim], 16B blocks XOR-swz (row&7)
    __shared__ bf16_t VtA[64 * 64], VtB[64 * 64];   // [dim][key], same swizzle
    const int tid = threadIdx.x;
    const int wave = tid >> 6, lane = tid & 63;
    const int ql = lane & 31;        // this lane's q (and D-col)
    const int hi = lane >> 5;
    const int bh = blockIdx.y;
    const int b = bh >> 4, h = bh & 15;
    const int qt = blockIdx.x;
    const size_t base = ((size_t)b * S) * DMODEL + (size_t)h * HDIM;
    const size_t vbase = (size_t)bh * HDIM * (size_t)S;

    // Q fragments (B-operand), 4 K-chunks of 16 dims: B[k=hi*8+e][col=ql]
    const int qrow = qt * 128 + wave * 32 + ql;
    bf16x8 qf[4];
#pragma unroll
    for (int kc = 0; kc < 4; ++kc)
        qf[kc] = *reinterpret_cast<const bf16x8*>(Qp + base + (size_t)qrow * DMODEL + kc * 16 + hi * 8);

    f32x16 o0{}, o1{};               // O^T[d][q=ql]: o0 d=0..31, o1 d=32..63
    float m_r = -1e30f, l_r = 0.f;   // per-lane = per-q (log2 domain)

    const int r0 = tid >> 3;
    const int swz = ((tid & 7) ^ (r0 & 7)) * 8;
    const bf16_t* Kb = Kp + base;
    const bf16_t* Vb = VtG + vbase;

    auto stageK = [&](int kv, bf16_t* buf) {
        gld_lds16(Kb + (size_t)(kv + r0) * DMODEL + swz, buf + wave * 512);
        gld_lds16(Kb + (size_t)(kv + r0 + 32) * DMODEL + swz, buf + 2048 + wave * 512);
    };
    auto stageV = [&](int kv, bf16_t* buf) {
        gld_lds16(Vb + (size_t)r0 * S + kv + swz, buf + wave * 512);
        gld_lds16(Vb + (size_t)(r0 + 32) * S + kv + swz, buf + 2048 + wave * 512);
    };

    // prologue: stage tile 0
    stageK(0, KsA);
    stageV(0, VtA);
    asm volatile("s_waitcnt vmcnt(0)" ::: "memory");
    __syncthreads();

    const int NT = S / 64;
    for (int t = 0; t < NT; ++t) {
        const bf16_t* Kc = (t & 1) ? KsB : KsA;
        const bf16_t* Vc = (t & 1) ? VtB : VtA;
        bf16_t* Kn = (t & 1) ? KsA : KsB;
        bf16_t* Vn = (t & 1) ? VtA : VtB;
        if (t + 1 < NT) {
            stageK((t + 1) * 64, Kn);
            stageV((t + 1) * 64, Vn);
        }

        // ---- QK^T: T[key][q] ; s0 = keys 0..31, s1 = keys 32..63 (row = ql / 32+ql) ----
        f32x16 s0{}, s1{};
        __builtin_amdgcn_s_setprio(1);
#pragma unroll
        for (int kc = 0; kc < 4; ++kc) {
            bf16x8 kf = *reinterpret_cast<const bf16x8*>(
                &Kc[ql * 64 + (((2 * kc + hi) ^ (ql & 7)) * 8)]);
            s0 = __builtin_amdgcn_mfma_f32_32x32x16_bf16(kf, qf[kc], s0, 0, 0, 0);
        }
#pragma unroll
        for (int kc = 0; kc < 4; ++kc) {
            bf16x8 kf = *reinterpret_cast<const bf16x8*>(
                &Kc[(32 + ql) * 64 + (((2 * kc + hi) ^ (ql & 7)) * 8)]);
            s1 = __builtin_amdgcn_mfma_f32_32x32x16_bf16(kf, qf[kc], s1, 0, 0, 0);
        }
        __builtin_amdgcn_s_setprio(0);

        // ---- in-lane softmax: lane holds 32 of 64 keys of q=ql; partner (l^32) the rest ----
        float mx = s0[0];
#pragma unroll
        for (int r = 1; r < 16; ++r) mx = fmaxf(mx, s0[r]);
#pragma unroll
        for (int r = 0; r < 16; ++r) mx = fmaxf(mx, s1[r]);
        mx = fmaxf(mx, __shfl_xor(mx, 32, 64));

        // T13 defer-max (log2 units): rescale all-in-lane (lane owns q's O regs)
        if (!__all(mx <= m_r + 8.f)) {
            float mnew = fmaxf(m_r, mx);
            float fsc = __builtin_amdgcn_exp2f(m_r - mnew);
            l_r *= fsc;
            m_r = mnew;
#pragma unroll
            for (int r = 0; r < 16; ++r) { o0[r] *= fsc; o1[r] *= fsc; }
        }

        float p0[16], p1[16];
        float ssum = 0.f;
#pragma unroll
        for (int r = 0; r < 16; ++r) {
            p0[r] = __builtin_amdgcn_exp2f(s0[r] - m_r);
            p1[r] = __builtin_amdgcn_exp2f(s1[r] - m_r);
            ssum += p0[r] + p1[r];
        }
        ssum += __shfl_xor(ssum, 32, 64);
        l_r += ssum;

        // ---- pack P to bf16 words: w[j][i] = keys {8j+4hi+2i, +1} of q=ql (j=0..7) ----
        unsigned w[8][2];
#pragma unroll
        for (int j = 0; j < 4; ++j) {
            w[j][0] = cvt_pk_bf16(p0[4 * j], p0[4 * j + 1]);
            w[j][1] = cvt_pk_bf16(p0[4 * j + 2], p0[4 * j + 3]);
            w[4 + j][0] = cvt_pk_bf16(p1[4 * j], p1[4 * j + 1]);
            w[4 + j][1] = cvt_pk_bf16(p1[4 * j + 2], p1[4 * j + 3]);
        }

        // ---- PV: per K-chunk kq (16 keys), build B-frag P^T[key=16kq+8hi+e][q=ql] ----
        // lane needs w[2kq+hi] from BOTH hi-halves: own copy + partner copy via shfl_xor(32).
        // send Y = w[2kq+1-hi] (static select), receive partner's w[2kq+hi].
#pragma unroll
        for (int kq = 0; kq < 4; ++kq) {
            unsigned own0 = hi ? w[2 * kq + 1][0] : w[2 * kq][0];
            unsigned own1 = hi ? w[2 * kq + 1][1] : w[2 * kq][1];
            unsigned y0 = hi ? w[2 * kq][0] : w[2 * kq + 1][0];
            unsigned y1 = hi ? w[2 * kq][1] : w[2 * kq + 1][1];
            y0 = (unsigned)__shfl_xor((int)y0, 32, 64);
            y1 = (unsigned)__shfl_xor((int)y1, 32, 64);
            union { unsigned u[4]; bf16x8 v; } pb;
            pb.u[0] = hi ? y0 : own0;      // regs 0,1 from hi=0 holder
            pb.u[1] = hi ? y1 : own1;
            pb.u[2] = hi ? own0 : y0;      // regs 2,3 from hi=1 holder
            pb.u[3] = hi ? own1 : y1;
            bf16x8 vf0 = *reinterpret_cast<const bf16x8*>(
                &Vc[ql * 64 + (((2 * kq + hi) ^ (ql & 7)) * 8)]);
            bf16x8 vf1 = *reinterpret_cast<const bf16x8*>(
                &Vc[(32 + ql) * 64 + (((2 * kq + hi) ^ (ql & 7)) * 8)]);
            __builtin_amdgcn_s_setprio(1);
            o0 = __builtin_amdgcn_mfma_f32_32x32x16_bf16(vf0, pb.v, o0, 0, 0, 0);
            o1 = __builtin_amdgcn_mfma_f32_32x32x16_bf16(vf1, pb.v, o1, 0, 0, 0);
            __builtin_amdgcn_s_setprio(0);
        }

        asm volatile("s_waitcnt vmcnt(0)" ::: "memory");
        __syncthreads();
    }

    // ---- epilogue: lane owns O^T[*][q=ql]; reg r -> d=(r&3)+8*(r>>2)+4*hi (+32 for o1) ----
    float inv = 1.f / l_r;
    bf16_t* Ao = AO + base + (size_t)qrow * DMODEL;
#pragma unroll
    for (int j = 0; j < 4; ++j) {
        uint2 u0, u1;
        u0.x = cvt_pk_bf16(o0[4 * j] * inv, o0[4 * j + 1] * inv);
        u0.y = cvt_pk_bf16(o0[4 * j + 2] * inv, o0[4 * j + 3] * inv);
        *reinterpret_cast<uint2*>(Ao + 8 * j + 4 * hi) = u0;
        u1.x = cvt_pk_bf16(o1[4 * j] * inv, o1[4 * j + 1] * inv);
        u1.y = cvt_pk_bf16(o1[4 * j + 2] * inv, o1[4 * j + 3] * inv);
        *reinterpret_cast<uint2*>(Ao + 32 + 8 * j + 4 * hi) = u1;
    }
}

extern "C" void kernel_launch(void* const* d_in, const int* in_sizes, int n_in,
                              void* d_out, int out_size, void* d_ws, size_t ws_size,
                              hipStream_t stream) {
    const float* q  = (const float*)d_in[0];
    const float* k  = (const float*)d_in[1];
    const float* v  = (const float*)d_in[2];
    const float* Wq = (const float*)d_in[3];
    const float* bq = (const float*)d_in[4];
    const float* Wk = (const float*)d_in[5];
    const float* bk = (const float*)d_in[6];
    const float* Wv = (const float*)d_in[7];
    const float* bv = (const float*)d_in[8];
    const float* Wo = (const float*)d_in[9];
    const float* bo = (const float*)d_in[10];

    const int M = in_sizes[0] / DMODEL;   // B*S
    const int S = 2048;
    const int B = M / S;

    bf16_t* ws  = (bf16_t*)d_ws;
    const size_t WSZ = (size_t)DMODEL * DMODEL;
    const size_t MSZ = (size_t)M * DMODEL;
    bf16_t* Wqb = ws;
    bf16_t* Wkb = Wqb + WSZ;
    bf16_t* Wvb = Wkb + WSZ;
    bf16_t* Wob = Wvb + WSZ;
    bf16_t* Qp  = Wob + WSZ;
    bf16_t* Kp  = Qp + MSZ;
    bf16_t* VtG = Kp + MSZ;
    bf16_t* AO  = VtG + MSZ;

    cast4<<<dim3(1024, 4), 256, 0, stream>>>(Wq, Wk, Wv, Wo, ws, DMODEL * DMODEL);

    const float qscale = 0.125f * 1.44269504088896f;   // 1/sqrt(64) * log2(e)
    dim3 gg(M / 128, DMODEL / 128);
    gemm_bt<1, 0><<<gg, 256, 0, stream>>>(q, Wqb, bq, Qp, M, DMODEL, DMODEL, qscale, S);
    gemm_bt<1, 0><<<gg, 256, 0, stream>>>(k, Wkb, bk, Kp, M, DMODEL, DMODEL, 1.0f, S);
    gemm_bt<1, 2><<<gg, 256, 0, stream>>>(v, Wvb, bv, VtG, M, DMODEL, DMODEL, 1.0f, S);

    attn_kernel<<<dim3(S / 128, B * NHEADS), 256, 0, stream>>>(Qp, Kp, VtG, AO, S);

    gemm_bt<0, 1><<<gg, 256, 0, stream>>>(AO, Wob, bo, d_out, M, DMODEL, DMODEL, 1.0f, S);
}

// Round 7
// 233.073 us; speedup vs baseline: 2.0419x; 1.0926x over previous
//
#include <hip/hip_runtime.h>
#include <hip/hip_bf16.h>

#define DMODEL 1024
#define NHEADS 16
#define HDIM 64

typedef __bf16 bf16_t;
typedef __bf16 bf16x8 __attribute__((ext_vector_type(8)));
typedef float  f32x4  __attribute__((ext_vector_type(4)));
typedef float  f32x16 __attribute__((ext_vector_type(16)));

__device__ __forceinline__ bf16_t f2bf(float f) {
    unsigned int u = __builtin_bit_cast(unsigned int, f);
    u += 0x7FFF + ((u >> 16) & 1);           // RNE
    unsigned short h = (unsigned short)(u >> 16);
    return __builtin_bit_cast(bf16_t, h);
}

__device__ __forceinline__ unsigned cvt_pk_bf16(float lo, float hi) {
    unsigned r;
    asm("v_cvt_pk_bf16_f32 %0, %1, %2" : "=v"(r) : "v"(lo), "v"(hi));
    return r;
}

__device__ __forceinline__ void gld_lds16(const bf16_t* g, bf16_t* l) {
    __builtin_amdgcn_global_load_lds(
        (const __attribute__((address_space(1))) unsigned int*)g,
        (__attribute__((address_space(3))) unsigned int*)l, 16, 0, 0);
}

// ---------------- fp32 -> bf16 cast: 4 weight matrices, one launch ----------------
__global__ __launch_bounds__(256) void cast4(const float* __restrict__ s0,
                                             const float* __restrict__ s1,
                                             const float* __restrict__ s2,
                                             const float* __restrict__ s3,
                                             bf16_t* __restrict__ d, int n) {
    int y = blockIdx.y;
    const float* s = (y == 0) ? s0 : (y == 1) ? s1 : (y == 2) ? s2 : s3;
    bf16_t* dst = d + (size_t)y * n;
    int i = blockIdx.x * blockDim.x + threadIdx.x;
    int stride = gridDim.x * blockDim.x;
    for (int idx = i * 4; idx < n; idx += stride * 4) {
        float4 v = *reinterpret_cast<const float4*>(s + idx);
        uint2 u;
        u.x = cvt_pk_bf16(v.x, v.y);
        u.y = cvt_pk_bf16(v.z, v.w);
        *reinterpret_cast<uint2*>(dst + idx) = u;
    }
}

// ---------------- merged QKV projection GEMM ----------------
// grid = (M/128, 8, 3); z selects {A, W, bias, scale, output mode}.
// C[m,n] = (sum_k A[m,k]*W[n,k] + bias[n]) * scale ; z=0 -> Qp (scaled), z=1 -> Kp,
// z=2 -> VtG transposed [B,H,D,S]. A fp32 reg-staged (T14), W bf16 via global_load_lds.
__global__ __launch_bounds__(256) void gemm_qkv(const float* __restrict__ qA,
                                                const float* __restrict__ kA,
                                                const float* __restrict__ vA,
                                                const bf16_t* __restrict__ Wall,
                                                const float* __restrict__ bq,
                                                const float* __restrict__ bk,
                                                const float* __restrict__ bv,
                                                bf16_t* __restrict__ Qp,
                                                bf16_t* __restrict__ Kp,
                                                bf16_t* __restrict__ VtG,
                                                int M, float qscale, int S) {
    __shared__ bf16_t Asmem[2][128 * 32];
    __shared__ bf16_t Bsmem[2][128 * 32];
    const int K = DMODEL, N = DMODEL;
    const int z = blockIdx.z;
    const float* Af = (z == 0) ? qA : (z == 1) ? kA : vA;
    const bf16_t* W = Wall + (size_t)z * DMODEL * DMODEL;
    const float* bias = (z == 0) ? bq : (z == 1) ? bk : bv;
    const float scale = (z == 0) ? qscale : 1.0f;

    const int m0 = blockIdx.x * 128;
    const int n0 = blockIdx.y * 128;
    const int tid = threadIdx.x;
    const int wave = tid >> 6, lane = tid & 63;
    const int wm = wave >> 1, wn = wave & 1;
    const int lr = lane & 15, lg = lane >> 4;
    const int srow = lane >> 2, scol = (lane & 3) * 8;   // gld_lds geometry
    const int a_r = tid >> 1, a_c = (tid & 1) * 16;      // fp32-A geometry

    float4 rA[4];
    f32x4 acc[4][4];
#pragma unroll
    for (int mi = 0; mi < 4; ++mi)
#pragma unroll
        for (int ni = 0; ni < 4; ++ni) acc[mi][ni] = (f32x4){0.f, 0.f, 0.f, 0.f};

    // ---- prologue: stage tile 0 ----
#pragma unroll
    for (int j = 0; j < 4; ++j)
        rA[j] = *reinterpret_cast<const float4*>(Af + (size_t)(m0 + a_r) * K + a_c + j * 4);
#pragma unroll
    for (int i = 0; i < 2; ++i) {
        int c = wave * 2 + i;
        gld_lds16(W + (size_t)(n0 + c * 16 + srow) * K + scol, &Bsmem[0][c * 512]);
    }
#pragma unroll
    for (int j = 0; j < 4; ++j) {
        uint2 u;
        u.x = cvt_pk_bf16(rA[j].x, rA[j].y);
        u.y = cvt_pk_bf16(rA[j].z, rA[j].w);
        *reinterpret_cast<uint2*>(&Asmem[0][a_r * 32 + a_c + j * 4]) = u;
    }
    asm volatile("s_waitcnt vmcnt(0)" ::: "memory");
    __syncthreads();

    const int nk = K / 32;
    for (int t = 0; t < nk; ++t) {
        const int cur = t & 1, nxt = cur ^ 1;
        const int ktn = (t + 1) * 32;
        const bool more = (t + 1 < nk);
        if (more) {
#pragma unroll
            for (int j = 0; j < 4; ++j)
                rA[j] = *reinterpret_cast<const float4*>(Af + (size_t)(m0 + a_r) * K + ktn + a_c + j * 4);
#pragma unroll
            for (int i = 0; i < 2; ++i) {
                int c = wave * 2 + i;
                gld_lds16(W + (size_t)(n0 + c * 16 + srow) * K + ktn + scol, &Bsmem[nxt][c * 512]);
            }
        }

        bf16x8 af[4], bfr[4];
#pragma unroll
        for (int mi = 0; mi < 4; ++mi)
            af[mi] = *reinterpret_cast<const bf16x8*>(&Asmem[cur][(wm * 64 + mi * 16 + lr) * 32 + lg * 8]);
#pragma unroll
        for (int ni = 0; ni < 4; ++ni)
            bfr[ni] = *reinterpret_cast<const bf16x8*>(&Bsmem[cur][(wn * 64 + ni * 16 + lr) * 32 + lg * 8]);
#pragma unroll
        for (int mi = 0; mi < 4; ++mi)
#pragma unroll
            for (int ni = 0; ni < 4; ++ni)
                acc[mi][ni] = __builtin_amdgcn_mfma_f32_16x16x32_bf16(af[mi], bfr[ni], acc[mi][ni], 0, 0, 0);

        if (more) {   // T14: convert+write AFTER compute
#pragma unroll
            for (int j = 0; j < 4; ++j) {
                uint2 u;
                u.x = cvt_pk_bf16(rA[j].x, rA[j].y);
                u.y = cvt_pk_bf16(rA[j].z, rA[j].w);
                *reinterpret_cast<uint2*>(&Asmem[nxt][a_r * 32 + a_c + j * 4]) = u;
            }
        }
        asm volatile("s_waitcnt vmcnt(0)" ::: "memory");
        __syncthreads();
    }

    // ---- epilogue ----
#pragma unroll
    for (int mi = 0; mi < 4; ++mi) {
        int row = m0 + wm * 64 + mi * 16 + lg * 4;
#pragma unroll
        for (int ni = 0; ni < 4; ++ni) {
            int col = n0 + wn * 64 + ni * 16 + lr;
            float bv_ = bias[col];
            if (z == 2) {   // transposed V output [B,H,D,S]
                union { bf16_t b[4]; uint2 u; } pq;
#pragma unroll
                for (int r = 0; r < 4; ++r) pq.b[r] = f2bf(acc[mi][ni][r] + bv_);
                int b_ = row / S, s_ = row % S;
                size_t addr = (((size_t)b_ * NHEADS + (col >> 6)) * HDIM + (col & 63)) * (size_t)S + s_;
                *reinterpret_cast<uint2*>(VtG + addr) = pq.u;
            } else {
                bf16_t* Cb = (z == 0) ? Qp : Kp;
#pragma unroll
                for (int r = 0; r < 4; ++r)
                    Cb[(size_t)(row + r) * N + col] = f2bf((acc[mi][ni][r] + bv_) * scale);
            }
        }
    }
}

// ---------------- output-projection GEMM (A bf16, out f32) ----------------
__global__ __launch_bounds__(256) void gemm_out(const bf16_t* __restrict__ Ab,
                                                const bf16_t* __restrict__ W,
                                                const float* __restrict__ bias,
                                                float* __restrict__ Cout,
                                                int M, int N, int K) {
    __shared__ bf16_t Asmem[2][128 * 32];
    __shared__ bf16_t Bsmem[2][128 * 32];
    const int m0 = blockIdx.x * 128;
    const int n0 = blockIdx.y * 128;
    const int tid = threadIdx.x;
    const int wave = tid >> 6, lane = tid & 63;
    const int wm = wave >> 1, wn = wave & 1;
    const int lr = lane & 15, lg = lane >> 4;
    const int srow = lane >> 2, scol = (lane & 3) * 8;

    f32x4 acc[4][4];
#pragma unroll
    for (int mi = 0; mi < 4; ++mi)
#pragma unroll
        for (int ni = 0; ni < 4; ++ni) acc[mi][ni] = (f32x4){0.f, 0.f, 0.f, 0.f};

#pragma unroll
    for (int i = 0; i < 2; ++i) {
        int c = wave * 2 + i;
        gld_lds16(Ab + (size_t)(m0 + c * 16 + srow) * K + scol, &Asmem[0][c * 512]);
        gld_lds16(W + (size_t)(n0 + c * 16 + srow) * K + scol, &Bsmem[0][c * 512]);
    }
    asm volatile("s_waitcnt vmcnt(0)" ::: "memory");
    __syncthreads();

    const int nk = K / 32;
    for (int t = 0; t < nk; ++t) {
        const int cur = t & 1, nxt = cur ^ 1;
        const int ktn = (t + 1) * 32;
        if (t + 1 < nk) {
#pragma unroll
            for (int i = 0; i < 2; ++i) {
                int c = wave * 2 + i;
                gld_lds16(Ab + (size_t)(m0 + c * 16 + srow) * K + ktn + scol, &Asmem[nxt][c * 512]);
                gld_lds16(W + (size_t)(n0 + c * 16 + srow) * K + ktn + scol, &Bsmem[nxt][c * 512]);
            }
        }
        bf16x8 af[4], bfr[4];
#pragma unroll
        for (int mi = 0; mi < 4; ++mi)
            af[mi] = *reinterpret_cast<const bf16x8*>(&Asmem[cur][(wm * 64 + mi * 16 + lr) * 32 + lg * 8]);
#pragma unroll
        for (int ni = 0; ni < 4; ++ni)
            bfr[ni] = *reinterpret_cast<const bf16x8*>(&Bsmem[cur][(wn * 64 + ni * 16 + lr) * 32 + lg * 8]);
#pragma unroll
        for (int mi = 0; mi < 4; ++mi)
#pragma unroll
            for (int ni = 0; ni < 4; ++ni)
                acc[mi][ni] = __builtin_amdgcn_mfma_f32_16x16x32_bf16(af[mi], bfr[ni], acc[mi][ni], 0, 0, 0);
        asm volatile("s_waitcnt vmcnt(0)" ::: "memory");
        __syncthreads();
    }

#pragma unroll
    for (int mi = 0; mi < 4; ++mi) {
        int row = m0 + wm * 64 + mi * 16 + lg * 4;
#pragma unroll
        for (int ni = 0; ni < 4; ++ni) {
            int col = n0 + wn * 64 + ni * 16 + lr;
            float bv = bias[col];
#pragma unroll
            for (int r = 0; r < 4; ++r)
                Cout[(size_t)(row + r) * N + col] = acc[mi][ni][r] + bv;
        }
    }
}

// ---------------- flash attention: 32x32 swapped-operand, lane-owns-q-row ----------------
// grid: x = S/128 (q tiles of 128), y = B*NHEADS. 256 threads = 4 waves, each 32 q rows.
// Qp/Kp: [B*S, DMODEL] bf16 (Q pre-scaled by 0.125*log2e). VtG: [B,H,D,S] bf16.
__global__ __launch_bounds__(256, 4) void attn_kernel(const bf16_t* __restrict__ Qp,
                                                      const bf16_t* __restrict__ Kp,
                                                      const bf16_t* __restrict__ VtG,
                                                      bf16_t* __restrict__ AO, int S) {
    __shared__ bf16_t KsA[64 * 64], KsB[64 * 64];   // [key][dim], 16B blocks XOR-swz (row&7)
    __shared__ bf16_t VtA[64 * 64], VtB[64 * 64];   // [dim][key], same swizzle
    const int tid = threadIdx.x;
    const int wave = tid >> 6, lane = tid & 63;
    const int ql = lane & 31;        // this lane's q (and D-col)
    const int hi = lane >> 5;
    const int bh = blockIdx.y;
    const int b = bh >> 4, h = bh & 15;
    const int qt = blockIdx.x;
    const size_t base = ((size_t)b * S) * DMODEL + (size_t)h * HDIM;
    const size_t vbase = (size_t)bh * HDIM * (size_t)S;

    const int qrow = qt * 128 + wave * 32 + ql;
    bf16x8 qf[4];
#pragma unroll
    for (int kc = 0; kc < 4; ++kc)
        qf[kc] = *reinterpret_cast<const bf16x8*>(Qp + base + (size_t)qrow * DMODEL + kc * 16 + hi * 8);

    f32x16 o0{}, o1{};               // O^T[d][q=ql]: o0 d=0..31, o1 d=32..63
    float m_r = -1e30f, l_r = 0.f;   // per-lane = per-q (log2 domain)

    const int r0 = tid >> 3;
    const int swz = ((tid & 7) ^ (r0 & 7)) * 8;
    const bf16_t* Kb = Kp + base;
    const bf16_t* Vb = VtG + vbase;

    auto stageK = [&](int kv, bf16_t* buf) {
        gld_lds16(Kb + (size_t)(kv + r0) * DMODEL + swz, buf + wave * 512);
        gld_lds16(Kb + (size_t)(kv + r0 + 32) * DMODEL + swz, buf + 2048 + wave * 512);
    };
    auto stageV = [&](int kv, bf16_t* buf) {
        gld_lds16(Vb + (size_t)r0 * S + kv + swz, buf + wave * 512);
        gld_lds16(Vb + (size_t)(r0 + 32) * S + kv + swz, buf + 2048 + wave * 512);
    };

    stageK(0, KsA);
    stageV(0, VtA);
    asm volatile("s_waitcnt vmcnt(0)" ::: "memory");
    __syncthreads();

    const int NT = S / 64;
    for (int t = 0; t < NT; ++t) {
        const bf16_t* Kc = (t & 1) ? KsB : KsA;
        const bf16_t* Vc = (t & 1) ? VtB : VtA;
        bf16_t* Kn = (t & 1) ? KsA : KsB;
        bf16_t* Vn = (t & 1) ? VtA : VtB;
        if (t + 1 < NT) {
            stageK((t + 1) * 64, Kn);
            stageV((t + 1) * 64, Vn);
        }

        // ---- QK^T: T[key][q] ; s0 = keys 0..31, s1 = keys 32..63 ----
        f32x16 s0{}, s1{};
        __builtin_amdgcn_s_setprio(1);
#pragma unroll
        for (int kc = 0; kc < 4; ++kc) {
            bf16x8 kf = *reinterpret_cast<const bf16x8*>(
                &Kc[ql * 64 + (((2 * kc + hi) ^ (ql & 7)) * 8)]);
            s0 = __builtin_amdgcn_mfma_f32_32x32x16_bf16(kf, qf[kc], s0, 0, 0, 0);
        }
#pragma unroll
        for (int kc = 0; kc < 4; ++kc) {
            bf16x8 kf = *reinterpret_cast<const bf16x8*>(
                &Kc[(32 + ql) * 64 + (((2 * kc + hi) ^ (ql & 7)) * 8)]);
            s1 = __builtin_amdgcn_mfma_f32_32x32x16_bf16(kf, qf[kc], s1, 0, 0, 0);
        }
        __builtin_amdgcn_s_setprio(0);

        // ---- in-lane softmax ----
        float mx = s0[0];
#pragma unroll
        for (int r = 1; r < 16; ++r) mx = fmaxf(mx, s0[r]);
#pragma unroll
        for (int r = 0; r < 16; ++r) mx = fmaxf(mx, s1[r]);
        mx = fmaxf(mx, __shfl_xor(mx, 32, 64));

        if (!__all(mx <= m_r + 8.f)) {   // T13 defer-max
            float mnew = fmaxf(m_r, mx);
            float fsc = __builtin_amdgcn_exp2f(m_r - mnew);
            l_r *= fsc;
            m_r = mnew;
#pragma unroll
            for (int r = 0; r < 16; ++r) { o0[r] *= fsc; o1[r] *= fsc; }
        }

        float p0[16], p1[16];
        float ssum = 0.f;
#pragma unroll
        for (int r = 0; r < 16; ++r) {
            p0[r] = __builtin_amdgcn_exp2f(s0[r] - m_r);
            p1[r] = __builtin_amdgcn_exp2f(s1[r] - m_r);
            ssum += p0[r] + p1[r];
        }
        ssum += __shfl_xor(ssum, 32, 64);
        l_r += ssum;

        // ---- pack P: w[j][i] = keys {8j+4hi+2i, +1} of q=ql ----
        unsigned w[8][2];
#pragma unroll
        for (int j = 0; j < 4; ++j) {
            w[j][0] = cvt_pk_bf16(p0[4 * j], p0[4 * j + 1]);
            w[j][1] = cvt_pk_bf16(p0[4 * j + 2], p0[4 * j + 3]);
            w[4 + j][0] = cvt_pk_bf16(p1[4 * j], p1[4 * j + 1]);
            w[4 + j][1] = cvt_pk_bf16(p1[4 * j + 2], p1[4 * j + 3]);
        }

        // ---- PV: per K-chunk kq, B-frag P^T[key=16kq+8hi+e][q=ql] ----
#pragma unroll
        for (int kq = 0; kq < 4; ++kq) {
            unsigned own0 = hi ? w[2 * kq + 1][0] : w[2 * kq][0];
            unsigned own1 = hi ? w[2 * kq + 1][1] : w[2 * kq][1];
            unsigned y0 = hi ? w[2 * kq][0] : w[2 * kq + 1][0];
            unsigned y1 = hi ? w[2 * kq][1] : w[2 * kq + 1][1];
            y0 = (unsigned)__shfl_xor((int)y0, 32, 64);
            y1 = (unsigned)__shfl_xor((int)y1, 32, 64);
            union { unsigned u[4]; bf16x8 v; } pb;
            pb.u[0] = hi ? y0 : own0;
            pb.u[1] = hi ? y1 : own1;
            pb.u[2] = hi ? own0 : y0;
            pb.u[3] = hi ? own1 : y1;
            bf16x8 vf0 = *reinterpret_cast<const bf16x8*>(
                &Vc[ql * 64 + (((2 * kq + hi) ^ (ql & 7)) * 8)]);
            bf16x8 vf1 = *reinterpret_cast<const bf16x8*>(
                &Vc[(32 + ql) * 64 + (((2 * kq + hi) ^ (ql & 7)) * 8)]);
            __builtin_amdgcn_s_setprio(1);
            o0 = __builtin_amdgcn_mfma_f32_32x32x16_bf16(vf0, pb.v, o0, 0, 0, 0);
            o1 = __builtin_amdgcn_mfma_f32_32x32x16_bf16(vf1, pb.v, o1, 0, 0, 0);
            __builtin_amdgcn_s_setprio(0);
        }

        asm volatile("s_waitcnt vmcnt(0)" ::: "memory");
        __syncthreads();
    }

    // ---- epilogue: reg r -> d=(r&3)+8*(r>>2)+4*hi (+32 for o1) ----
    float inv = 1.f / l_r;
    bf16_t* Ao = AO + base + (size_t)qrow * DMODEL;
#pragma unroll
    for (int j = 0; j < 4; ++j) {
        uint2 u0, u1;
        u0.x = cvt_pk_bf16(o0[4 * j] * inv, o0[4 * j + 1] * inv);
        u0.y = cvt_pk_bf16(o0[4 * j + 2] * inv, o0[4 * j + 3] * inv);
        *reinterpret_cast<uint2*>(Ao + 8 * j + 4 * hi) = u0;
        u1.x = cvt_pk_bf16(o1[4 * j] * inv, o1[4 * j + 1] * inv);
        u1.y = cvt_pk_bf16(o1[4 * j + 2] * inv, o1[4 * j + 3] * inv);
        *reinterpret_cast<uint2*>(Ao + 32 + 8 * j + 4 * hi) = u1;
    }
}

extern "C" void kernel_launch(void* const* d_in, const int* in_sizes, int n_in,
                              void* d_out, int out_size, void* d_ws, size_t ws_size,
                              hipStream_t stream) {
    const float* q  = (const float*)d_in[0];
    const float* k  = (const float*)d_in[1];
    const float* v  = (const float*)d_in[2];
    const float* Wq = (const float*)d_in[3];
    const float* bq = (const float*)d_in[4];
    const float* Wk = (const float*)d_in[5];
    const float* bk = (const float*)d_in[6];
    const float* Wv = (const float*)d_in[7];
    const float* bv = (const float*)d_in[8];
    const float* Wo = (const float*)d_in[9];
    const float* bo = (const float*)d_in[10];

    const int M = in_sizes[0] / DMODEL;   // B*S
    const int S = 2048;
    const int B = M / S;

    bf16_t* ws  = (bf16_t*)d_ws;
    const size_t WSZ = (size_t)DMODEL * DMODEL;
    const size_t MSZ = (size_t)M * DMODEL;
    bf16_t* Wqb = ws;                      // Wall = [Wq|Wk|Wv|Wo] bf16
    bf16_t* Wob = Wqb + 3 * WSZ;
    bf16_t* Qp  = Wob + WSZ;
    bf16_t* Kp  = Qp + MSZ;
    bf16_t* VtG = Kp + MSZ;
    bf16_t* AO  = VtG + MSZ;

    cast4<<<dim3(1024, 4), 256, 0, stream>>>(Wq, Wk, Wv, Wo, ws, DMODEL * DMODEL);

    const float qscale = 0.125f * 1.44269504088896f;   // 1/sqrt(64) * log2(e)
    gemm_qkv<<<dim3(M / 128, DMODEL / 128, 3), 256, 0, stream>>>(
        q, k, v, Wqb, bq, bk, bv, Qp, Kp, VtG, M, qscale, S);

    attn_kernel<<<dim3(S / 128, B * NHEADS), 256, 0, stream>>>(Qp, Kp, VtG, AO, S);

    gemm_out<<<dim3(M / 128, DMODEL / 128), 256, 0, stream>>>(
        AO, Wob, bo, (float*)d_out, M, DMODEL, DMODEL);
}